// Round 1
// baseline (1401.768 us; speedup 1.0000x reference)
//
#include <hip/hip_runtime.h>
#include <math.h>

#define N_ENT 100000
#define N_EDGE 500000
#define N_REL 200
// DIM=64, HEADS=4, HD=256

// ---------------------------------------------------------------------------
// p[n,h] = sum_d tanh( (embed[n,:] @ W)[h*64+d] ) * att[h,d]
// block = 256 threads = 4 waves; wave h handles head h, lane d handles dim d.
// 64 entities per block staged in LDS; W column kept in 64 VGPRs.
__global__ __launch_bounds__(256) void proj_kernel(
    const float* __restrict__ embed,   // [nrows,64]
    const float* __restrict__ W,       // [64,256]
    const float* __restrict__ att,     // [4,64]
    float* __restrict__ p,             // [nrows,4]
    int nrows)
{
    __shared__ float e_lds[64][64];
    const int h = threadIdx.x >> 6;
    const int d = threadIdx.x & 63;
    const int base = blockIdx.x * 64;

    float wcol[64];
#pragma unroll
    for (int k = 0; k < 64; ++k)
        wcol[k] = W[k * 256 + h * 64 + d];
    const float attv = att[h * 64 + d];

    const int tile = min(64, nrows - base);
    for (int idx = threadIdx.x; idx < tile * 64; idx += 256)
        e_lds[idx >> 6][idx & 63] = embed[(size_t)base * 64 + idx];
    __syncthreads();

    for (int i = 0; i < tile; ++i) {
        float dot = 0.f;
#pragma unroll
        for (int k = 0; k < 64; ++k)
            dot = fmaf(e_lds[i][k], wcol[k], dot);
        float v = tanhf(dot) * attv;
#pragma unroll
        for (int off = 32; off > 0; off >>= 1)
            v += __shfl_down(v, off, 64);
        if (d == 0) p[(size_t)(base + i) * 4 + h] = v;
    }
}

// ---------------------------------------------------------------------------
// Per-edge: score = leaky_relu(p_h[head]+p_t[tail]+p_r[rel]); e = exp(score).
// Accumulate denom per (head-entity, head) and per-entity degree counts.
__global__ __launch_bounds__(256) void edge_score_kernel(
    const int* __restrict__ eidx,      // [2,E] row0=head row1=tail
    const int* __restrict__ etype,     // [E]
    const float* __restrict__ ph, const float* __restrict__ pt,
    const float* __restrict__ pr,
    float* __restrict__ esc,           // [E,4]
    float* __restrict__ denom,         // [N,4]
    int* __restrict__ counts)          // [N]
{
    int e = blockIdx.x * 256 + threadIdx.x;
    if (e >= N_EDGE) return;
    int hn = eidx[e];
    int tn = eidx[N_EDGE + e];
    int r  = etype[e];
    float4 a = *(const float4*)(ph + (size_t)hn * 4);
    float4 b = *(const float4*)(pt + (size_t)tn * 4);
    float4 c = *(const float4*)(pr + (size_t)r * 4);
    float s0 = a.x + b.x + c.x;
    float s1 = a.y + b.y + c.y;
    float s2 = a.z + b.z + c.z;
    float s3 = a.w + b.w + c.w;
    s0 = s0 >= 0.f ? s0 : 0.01f * s0;
    s1 = s1 >= 0.f ? s1 : 0.01f * s1;
    s2 = s2 >= 0.f ? s2 : 0.01f * s2;
    s3 = s3 >= 0.f ? s3 : 0.01f * s3;
    float e0 = expf(s0), e1 = expf(s1), e2 = expf(s2), e3 = expf(s3);
    *(float4*)(esc + (size_t)e * 4) = make_float4(e0, e1, e2, e3);
    atomicAdd(&denom[(size_t)hn * 4 + 0], e0);
    atomicAdd(&denom[(size_t)hn * 4 + 1], e1);
    atomicAdd(&denom[(size_t)hn * 4 + 2], e2);
    atomicAdd(&denom[(size_t)hn * 4 + 3], e3);
    atomicAdd(&counts[hn], 1);
}

// ---------------------------------------------------------------------------
// Exclusive scan of counts[N_ENT] -> row_start[N_ENT+1]. Single block.
__global__ __launch_bounds__(1024) void scan_kernel(
    const int* __restrict__ counts, int* __restrict__ row_start)
{
    __shared__ int buf[1024];
    __shared__ int carry;
    if (threadIdx.x == 0) carry = 0;
    __syncthreads();
    for (int base = 0; base < N_ENT; base += 1024) {
        int i = base + (int)threadIdx.x;
        int v = (i < N_ENT) ? counts[i] : 0;
        buf[threadIdx.x] = v;
        __syncthreads();
        for (int off = 1; off < 1024; off <<= 1) {
            int t = (threadIdx.x >= (unsigned)off) ? buf[threadIdx.x - off] : 0;
            __syncthreads();
            buf[threadIdx.x] += t;
            __syncthreads();
        }
        int incl = buf[threadIdx.x];
        if (i < N_ENT) row_start[i] = carry + (incl - v);
        __syncthreads();
        if (threadIdx.x == 1023) carry += incl;
        __syncthreads();
    }
    if (threadIdx.x == 0) row_start[N_ENT] = carry;
}

// ---------------------------------------------------------------------------
// Normalize att and scatter edges into CSR (rows = head entity).
__global__ __launch_bounds__(256) void scatter_kernel(
    const int* __restrict__ eidx,
    const float* __restrict__ esc, const float* __restrict__ denom,
    const int* __restrict__ row_start, int* __restrict__ cursor,
    int* __restrict__ csr_col, float* __restrict__ csr_a)
{
    int e = blockIdx.x * 256 + threadIdx.x;
    if (e >= N_EDGE) return;
    int hn = eidx[e];
    int tn = eidx[N_EDGE + e];
    float4 ev = *(const float4*)(esc + (size_t)e * 4);
    float4 dn = *(const float4*)(denom + (size_t)hn * 4);
    float4 a;
    a.x = 0.9f * ev.x / (dn.x + 1e-16f);
    a.y = 0.9f * ev.y / (dn.y + 1e-16f);
    a.z = 0.9f * ev.z / (dn.z + 1e-16f);
    a.w = 0.9f * ev.w / (dn.w + 1e-16f);
    int pos = row_start[hn] + atomicAdd(&cursor[hn], 1);
    csr_col[pos] = tn;
    *(float4*)(csr_a + (size_t)pos * 4) = a;
}

// ---------------------------------------------------------------------------
// Z[n, h*64+d] = embed[n, d]  (broadcast across heads)
__global__ __launch_bounds__(256) void initZ_kernel(
    const float* __restrict__ emb, float* __restrict__ Z)
{
    int n = blockIdx.x;
    int t = threadIdx.x;
    Z[(size_t)n * 256 + t] = emb[(size_t)n * 64 + (t & 63)];
}

// ---------------------------------------------------------------------------
// One SpMM step: Zout[n,:] = sum_{e in row n} a[e,h] * Zin[col_e, h, :] + 0.1*Z0[n,:]
// wave per entity; lane handles float4 (elements 4*lane .. 4*lane+3), h = lane/16.
__global__ __launch_bounds__(256) void spmm_kernel(
    const float* __restrict__ Zin, const float* __restrict__ emb,
    const int* __restrict__ row_start, const int* __restrict__ csr_col,
    const float* __restrict__ csr_a, float* __restrict__ Zout)
{
    const int wave = threadIdx.x >> 6;
    const int lane = threadIdx.x & 63;
    const int n = blockIdx.x * 4 + wave;
    if (n >= N_ENT) return;
    const int h = lane >> 4;

    const float4* e4 = (const float4*)emb;   // [N][16]
    float4 z0 = e4[(size_t)n * 16 + (lane & 15)];
    float4 acc = make_float4(0.1f * z0.x, 0.1f * z0.y, 0.1f * z0.z, 0.1f * z0.w);

    const int s = row_start[n];
    const int epos_end = row_start[n + 1];
    for (int p = s; p < epos_end; ++p) {
        int c = csr_col[p];
        float av = csr_a[(size_t)p * 4 + h];
        float4 z = *(const float4*)(Zin + (size_t)c * 256 + 4 * lane);
        acc.x = fmaf(av, z.x, acc.x);
        acc.y = fmaf(av, z.y, acc.y);
        acc.z = fmaf(av, z.z, acc.z);
        acc.w = fmaf(av, z.w, acc.w);
    }
    *(float4*)(Zout + (size_t)n * 256 + 4 * lane) = acc;
}

// ---------------------------------------------------------------------------
// out[n,d] = sum_k Z[n,k] * Wo[k,d]   (wave per entity, lane = d)
__global__ __launch_bounds__(256) void outproj_kernel(
    const float* __restrict__ Z, const float* __restrict__ Wo,
    float* __restrict__ out)
{
    const int wave = threadIdx.x >> 6;
    const int lane = threadIdx.x & 63;
    const int n = blockIdx.x * 4 + wave;
    if (n >= N_ENT) return;
    const float* z = Z + (size_t)n * 256;
    float acc = 0.f;
#pragma unroll
    for (int k4 = 0; k4 < 64; ++k4) {
        float4 zv = *(const float4*)(z + 4 * k4);
        acc = fmaf(zv.x, Wo[(4 * k4 + 0) * 64 + lane], acc);
        acc = fmaf(zv.y, Wo[(4 * k4 + 1) * 64 + lane], acc);
        acc = fmaf(zv.z, Wo[(4 * k4 + 2) * 64 + lane], acc);
        acc = fmaf(zv.w, Wo[(4 * k4 + 3) * 64 + lane], acc);
    }
    out[(size_t)n * 64 + lane] = acc;
}

// ---------------------------------------------------------------------------
extern "C" void kernel_launch(void* const* d_in, const int* in_sizes, int n_in,
                              void* d_out, int out_size, void* d_ws, size_t ws_size,
                              hipStream_t stream)
{
    const float* entity = (const float*)d_in[0];
    const float* rel    = (const float*)d_in[1];
    const float* W_h    = (const float*)d_in[2];
    const float* W_t    = (const float*)d_in[3];
    const float* W_r    = (const float*)d_in[4];
    const float* att_h  = (const float*)d_in[5];
    const float* att_t  = (const float*)d_in[6];
    const float* att_r  = (const float*)d_in[7];
    const float* W_o    = (const float*)d_in[8];
    const int*   eidx   = (const int*)d_in[9];   // [2,E] int32
    const int*   etype  = (const int*)d_in[10];  // [E]
    float* out = (float*)d_out;

    char* ws = (char*)d_ws;
    size_t off = 0;
    auto alloc = [&](size_t bytes) -> void* {
        void* p = ws + off;
        off += (bytes + 255) & ~(size_t)255;
        return p;
    };
    float* p_h      = (float*)alloc((size_t)N_ENT * 4 * 4);
    float* p_t      = (float*)alloc((size_t)N_ENT * 4 * 4);
    float* p_r      = (float*)alloc((size_t)N_REL * 4 * 4);
    float* esc      = (float*)alloc((size_t)N_EDGE * 4 * 4);
    float* denom    = (float*)alloc((size_t)N_ENT * 4 * 4);
    int*   counts   = (int*)alloc((size_t)N_ENT * 4);
    int*   row_start= (int*)alloc(((size_t)N_ENT + 1) * 4);
    int*   cursor   = (int*)alloc((size_t)N_ENT * 4);
    int*   csr_col  = (int*)alloc((size_t)N_EDGE * 4);
    float* csr_a    = (float*)alloc((size_t)N_EDGE * 4 * 4);
    float* Za       = (float*)alloc((size_t)N_ENT * 256 * 4);
    float* Zb       = (float*)alloc((size_t)N_ENT * 256 * 4);

    // zero accumulators (ws is NOT re-poisoned/zeroed between replays)
    hipMemsetAsync(denom,  0, (size_t)N_ENT * 4 * 4, stream);
    hipMemsetAsync(counts, 0, (size_t)N_ENT * 4, stream);
    hipMemsetAsync(cursor, 0, (size_t)N_ENT * 4, stream);

    // per-entity / per-relation attention projections
    proj_kernel<<<(N_ENT + 63) / 64, 256, 0, stream>>>(entity, W_h, att_h, p_h, N_ENT);
    proj_kernel<<<(N_ENT + 63) / 64, 256, 0, stream>>>(entity, W_t, att_t, p_t, N_ENT);
    proj_kernel<<<(N_REL + 63) / 64, 256, 0, stream>>>(rel,    W_r, att_r, p_r, N_REL);

    // edge scores + softmax denominators + degree histogram
    edge_score_kernel<<<(N_EDGE + 255) / 256, 256, 0, stream>>>(
        eidx, etype, p_h, p_t, p_r, esc, denom, counts);

    // CSR build
    scan_kernel<<<1, 1024, 0, stream>>>(counts, row_start);
    scatter_kernel<<<(N_EDGE + 255) / 256, 256, 0, stream>>>(
        eidx, esc, denom, row_start, cursor, csr_col, csr_a);

    // power iteration
    initZ_kernel<<<N_ENT, 256, 0, stream>>>(entity, Za);
    spmm_kernel<<<N_ENT / 4, 256, 0, stream>>>(Za, entity, row_start, csr_col, csr_a, Zb);
    spmm_kernel<<<N_ENT / 4, 256, 0, stream>>>(Zb, entity, row_start, csr_col, csr_a, Za);
    spmm_kernel<<<N_ENT / 4, 256, 0, stream>>>(Za, entity, row_start, csr_col, csr_a, Zb);
    spmm_kernel<<<N_ENT / 4, 256, 0, stream>>>(Zb, entity, row_start, csr_col, csr_a, Za);
    spmm_kernel<<<N_ENT / 4, 256, 0, stream>>>(Za, entity, row_start, csr_col, csr_a, Zb);

    // output projection
    outproj_kernel<<<N_ENT / 4, 256, 0, stream>>>(Zb, W_o, out);
}

// Round 2
// 1012.397 us; speedup vs baseline: 1.3846x; 1.3846x over previous
//
#include <hip/hip_runtime.h>
#include <math.h>

#define N_ENT 100000
#define N_EDGE 500000
#define N_REL 200
// DIM=64, HEADS=4, HD=256

__device__ __forceinline__ float fast_tanh(float x) {
    float xc = fminf(x, 15.f);
    float e = __expf(2.f * xc);
    return (e - 1.f) / (e + 1.f);
}

// ---------------------------------------------------------------------------
// p[n,h] = sum_d tanh( (embed[n,:] @ W)[h*64+d] ) * att[h,d]
__global__ __launch_bounds__(256) void proj_kernel(
    const float* __restrict__ embed,   // [nrows,64]
    const float* __restrict__ W,       // [64,256]
    const float* __restrict__ att,     // [4,64]
    float* __restrict__ p,             // [nrows,4]
    int nrows)
{
    __shared__ float e_lds[64][64];
    const int h = threadIdx.x >> 6;
    const int d = threadIdx.x & 63;
    const int base = blockIdx.x * 64;

    float wcol[64];
#pragma unroll
    for (int k = 0; k < 64; ++k)
        wcol[k] = W[k * 256 + h * 64 + d];
    const float attv = att[h * 64 + d];

    const int tile = min(64, nrows - base);
    for (int idx = threadIdx.x; idx < tile * 64; idx += 256)
        e_lds[idx >> 6][idx & 63] = embed[(size_t)base * 64 + idx];
    __syncthreads();

    for (int i = 0; i < tile; ++i) {
        float dot = 0.f;
#pragma unroll
        for (int k = 0; k < 64; ++k)
            dot = fmaf(e_lds[i][k], wcol[k], dot);
        float v = fast_tanh(dot) * attv;
#pragma unroll
        for (int off = 32; off > 0; off >>= 1)
            v += __shfl_down(v, off, 64);
        if (d == 0) p[(size_t)(base + i) * 4 + h] = v;
    }
}

// ---------------------------------------------------------------------------
__global__ __launch_bounds__(256) void edge_score_kernel(
    const int* __restrict__ eidx,      // [2,E] row0=head row1=tail
    const int* __restrict__ etype,     // [E]
    const float* __restrict__ ph, const float* __restrict__ pt,
    const float* __restrict__ pr,
    float* __restrict__ esc,           // [E,4]
    float* __restrict__ denom,         // [N,4]
    int* __restrict__ counts)          // [N]
{
    int e = blockIdx.x * 256 + threadIdx.x;
    if (e >= N_EDGE) return;
    int hn = eidx[e];
    int tn = eidx[N_EDGE + e];
    int r  = etype[e];
    float4 a = *(const float4*)(ph + (size_t)hn * 4);
    float4 b = *(const float4*)(pt + (size_t)tn * 4);
    float4 c = *(const float4*)(pr + (size_t)r * 4);
    float s0 = a.x + b.x + c.x;
    float s1 = a.y + b.y + c.y;
    float s2 = a.z + b.z + c.z;
    float s3 = a.w + b.w + c.w;
    s0 = s0 >= 0.f ? s0 : 0.01f * s0;
    s1 = s1 >= 0.f ? s1 : 0.01f * s1;
    s2 = s2 >= 0.f ? s2 : 0.01f * s2;
    s3 = s3 >= 0.f ? s3 : 0.01f * s3;
    float e0 = __expf(s0), e1 = __expf(s1), e2 = __expf(s2), e3 = __expf(s3);
    *(float4*)(esc + (size_t)e * 4) = make_float4(e0, e1, e2, e3);
    atomicAdd(&denom[(size_t)hn * 4 + 0], e0);
    atomicAdd(&denom[(size_t)hn * 4 + 1], e1);
    atomicAdd(&denom[(size_t)hn * 4 + 2], e2);
    atomicAdd(&denom[(size_t)hn * 4 + 3], e3);
    atomicAdd(&counts[hn], 1);
}

// ---------------------------------------------------------------------------
// Exclusive scan of counts[N_ENT] -> row_start[N_ENT+1]. Single block,
// wave-shuffle based: 4 elems/thread, 2 barriers per 4096-elem tile.
__global__ __launch_bounds__(1024) void scan_kernel(
    const int* __restrict__ counts, int* __restrict__ row_start)
{
    __shared__ int wsum[16];
    __shared__ int carry_s;
    const int lane = threadIdx.x & 63;
    const int wid  = threadIdx.x >> 6;
    if (threadIdx.x == 0) carry_s = 0;
    __syncthreads();
    for (int base = 0; base < N_ENT; base += 4096) {
        int i0 = base + (int)threadIdx.x * 4;
        int4 v = make_int4(0, 0, 0, 0);
        if (i0 + 3 < N_ENT) v = *(const int4*)(counts + i0);
        else {
            if (i0 + 0 < N_ENT) v.x = counts[i0 + 0];
            if (i0 + 1 < N_ENT) v.y = counts[i0 + 1];
            if (i0 + 2 < N_ENT) v.z = counts[i0 + 2];
            if (i0 + 3 < N_ENT) v.w = counts[i0 + 3];
        }
        int s1 = v.x + v.y, s2 = s1 + v.z, tsum = s2 + v.w;
        int incl = tsum;
#pragma unroll
        for (int off = 1; off < 64; off <<= 1) {
            int t = __shfl_up(incl, off, 64);
            if (lane >= off) incl += t;
        }
        if (lane == 63) wsum[wid] = incl;
        __syncthreads();                              // A
        int wave_off = 0;
#pragma unroll
        for (int w = 0; w < 16; ++w)
            wave_off += (w < wid) ? wsum[w] : 0;
        int carry = carry_s;
        int excl = carry + wave_off + (incl - tsum);
        if (i0 + 3 < N_ENT) {
            *(int4*)(row_start + i0) = make_int4(excl, excl + v.x, excl + s1, excl + s2);
        } else {
            if (i0 + 0 < N_ENT) row_start[i0 + 0] = excl;
            if (i0 + 1 < N_ENT) row_start[i0 + 1] = excl + v.x;
            if (i0 + 2 < N_ENT) row_start[i0 + 2] = excl + s1;
            if (i0 + 3 < N_ENT) row_start[i0 + 3] = excl + s2;
        }
        __syncthreads();                              // B
        if (threadIdx.x == 1023) carry_s = carry + wave_off + incl;
    }
    __syncthreads();
    if (threadIdx.x == 0) row_start[N_ENT] = carry_s;
}

// ---------------------------------------------------------------------------
__global__ __launch_bounds__(256) void scatter_kernel(
    const int* __restrict__ eidx,
    const float* __restrict__ esc, const float* __restrict__ denom,
    const int* __restrict__ row_start, int* __restrict__ cursor,
    int* __restrict__ csr_col, float* __restrict__ csr_a)
{
    int e = blockIdx.x * 256 + threadIdx.x;
    if (e >= N_EDGE) return;
    int hn = eidx[e];
    int tn = eidx[N_EDGE + e];
    float4 ev = *(const float4*)(esc + (size_t)e * 4);
    float4 dn = *(const float4*)(denom + (size_t)hn * 4);
    float4 a;
    a.x = 0.9f * ev.x / (dn.x + 1e-16f);
    a.y = 0.9f * ev.y / (dn.y + 1e-16f);
    a.z = 0.9f * ev.z / (dn.z + 1e-16f);
    a.w = 0.9f * ev.w / (dn.w + 1e-16f);
    int pos = row_start[hn] + atomicAdd(&cursor[hn], 1);
    csr_col[pos] = tn;
    *(float4*)(csr_a + (size_t)pos * 4) = a;
}

// ---------------------------------------------------------------------------
// SpMM step. FIRST=true reads Zin rows as broadcast of emb (256B gathers).
// wave per entity; lane handles float4, h = lane/16. Unroll-2, dual acc.
template <bool FIRST>
__global__ __launch_bounds__(256) void spmm_kernel(
    const float* __restrict__ Zin, const float* __restrict__ emb,
    const int* __restrict__ row_start, const int* __restrict__ csr_col,
    const float* __restrict__ csr_a, float* __restrict__ Zout)
{
    const int wave = threadIdx.x >> 6;
    const int lane = threadIdx.x & 63;
    const int n = blockIdx.x * 4 + wave;
    const int h = lane >> 4;

    const float4* e4 = (const float4*)emb;   // [N][16]
    float4 z0 = e4[(size_t)n * 16 + (lane & 15)];
    float4 acc0 = make_float4(0.1f * z0.x, 0.1f * z0.y, 0.1f * z0.z, 0.1f * z0.w);
    float4 acc1 = make_float4(0.f, 0.f, 0.f, 0.f);

    const int s   = row_start[n];
    const int end = row_start[n + 1];

    auto zrow = [&](int c) -> float4 {
        if (FIRST)
            return *(const float4*)(emb + (size_t)c * 64 + 4 * (lane & 15));
        else
            return *(const float4*)(Zin + (size_t)c * 256 + 4 * lane);
    };

    int p = s;
    for (; p + 2 <= end; p += 2) {
        int c0 = csr_col[p];
        int c1 = csr_col[p + 1];
        float a0 = csr_a[(size_t)p * 4 + h];
        float a1 = csr_a[(size_t)(p + 1) * 4 + h];
        float4 za = zrow(c0);
        float4 zb = zrow(c1);
        acc0.x = fmaf(a0, za.x, acc0.x);
        acc0.y = fmaf(a0, za.y, acc0.y);
        acc0.z = fmaf(a0, za.z, acc0.z);
        acc0.w = fmaf(a0, za.w, acc0.w);
        acc1.x = fmaf(a1, zb.x, acc1.x);
        acc1.y = fmaf(a1, zb.y, acc1.y);
        acc1.z = fmaf(a1, zb.z, acc1.z);
        acc1.w = fmaf(a1, zb.w, acc1.w);
    }
    if (p < end) {
        int c0 = csr_col[p];
        float a0 = csr_a[(size_t)p * 4 + h];
        float4 za = zrow(c0);
        acc0.x = fmaf(a0, za.x, acc0.x);
        acc0.y = fmaf(a0, za.y, acc0.y);
        acc0.z = fmaf(a0, za.z, acc0.z);
        acc0.w = fmaf(a0, za.w, acc0.w);
    }
    acc0.x += acc1.x; acc0.y += acc1.y; acc0.z += acc1.z; acc0.w += acc1.w;
    *(float4*)(Zout + (size_t)n * 256 + 4 * lane) = acc0;
}

// ---------------------------------------------------------------------------
// out[100000,64] = Z[100000,256] @ Wo[256,64].
// Block: 64 entities. Wo staged in LDS (64KB). Thread computes 4 ent x 4 dim.
__global__ __launch_bounds__(256) void outproj_kernel(
    const float* __restrict__ Z, const float* __restrict__ Wo,
    float* __restrict__ out)
{
    __shared__ float wo_lds[256][64];
    const int t = threadIdx.x;
    {
        const float4* src = (const float4*)Wo;
        float4* dst = (float4*)&wo_lds[0][0];
#pragma unroll
        for (int i = 0; i < 16; ++i)
            dst[t + 256 * i] = src[t + 256 * i];
    }
    __syncthreads();

    const int base = blockIdx.x * 64;
    const int er = t & 15;          // entity residue: rows er, er+16, er+32, er+48
    const int d0 = (t >> 4) * 4;    // output dim group

    int r0 = min(base + er + 0,  N_ENT - 1);
    int r1 = min(base + er + 16, N_ENT - 1);
    int r2 = min(base + er + 32, N_ENT - 1);
    int r3 = min(base + er + 48, N_ENT - 1);
    const float* zp0 = Z + (size_t)r0 * 256;
    const float* zp1 = Z + (size_t)r1 * 256;
    const float* zp2 = Z + (size_t)r2 * 256;
    const float* zp3 = Z + (size_t)r3 * 256;

    float acc[4][4] = {};
    for (int k4 = 0; k4 < 64; ++k4) {
        float4 z0 = *(const float4*)(zp0 + 4 * k4);
        float4 z1 = *(const float4*)(zp1 + 4 * k4);
        float4 z2 = *(const float4*)(zp2 + 4 * k4);
        float4 z3 = *(const float4*)(zp3 + 4 * k4);
#pragma unroll
        for (int j = 0; j < 4; ++j) {
            float4 wv = *(const float4*)&wo_lds[4 * k4 + j][d0];
            float zj0 = ((const float*)&z0)[j];
            float zj1 = ((const float*)&z1)[j];
            float zj2 = ((const float*)&z2)[j];
            float zj3 = ((const float*)&z3)[j];
            acc[0][0] = fmaf(zj0, wv.x, acc[0][0]);
            acc[0][1] = fmaf(zj0, wv.y, acc[0][1]);
            acc[0][2] = fmaf(zj0, wv.z, acc[0][2]);
            acc[0][3] = fmaf(zj0, wv.w, acc[0][3]);
            acc[1][0] = fmaf(zj1, wv.x, acc[1][0]);
            acc[1][1] = fmaf(zj1, wv.y, acc[1][1]);
            acc[1][2] = fmaf(zj1, wv.z, acc[1][2]);
            acc[1][3] = fmaf(zj1, wv.w, acc[1][3]);
            acc[2][0] = fmaf(zj2, wv.x, acc[2][0]);
            acc[2][1] = fmaf(zj2, wv.y, acc[2][1]);
            acc[2][2] = fmaf(zj2, wv.z, acc[2][2]);
            acc[2][3] = fmaf(zj2, wv.w, acc[2][3]);
            acc[3][0] = fmaf(zj3, wv.x, acc[3][0]);
            acc[3][1] = fmaf(zj3, wv.y, acc[3][1]);
            acc[3][2] = fmaf(zj3, wv.z, acc[3][2]);
            acc[3][3] = fmaf(zj3, wv.w, acc[3][3]);
        }
    }
#pragma unroll
    for (int i = 0; i < 4; ++i) {
        int row = base + er + 16 * i;
        if (row < N_ENT) {
            *(float4*)(out + (size_t)row * 64 + d0) =
                make_float4(acc[i][0], acc[i][1], acc[i][2], acc[i][3]);
        }
    }
}

// ---------------------------------------------------------------------------
extern "C" void kernel_launch(void* const* d_in, const int* in_sizes, int n_in,
                              void* d_out, int out_size, void* d_ws, size_t ws_size,
                              hipStream_t stream)
{
    const float* entity = (const float*)d_in[0];
    const float* rel    = (const float*)d_in[1];
    const float* W_h    = (const float*)d_in[2];
    const float* W_t    = (const float*)d_in[3];
    const float* W_r    = (const float*)d_in[4];
    const float* att_h  = (const float*)d_in[5];
    const float* att_t  = (const float*)d_in[6];
    const float* att_r  = (const float*)d_in[7];
    const float* W_o    = (const float*)d_in[8];
    const int*   eidx   = (const int*)d_in[9];   // [2,E]
    const int*   etype  = (const int*)d_in[10];  // [E]
    float* out = (float*)d_out;

    char* ws = (char*)d_ws;
    size_t off = 0;
    auto alloc = [&](size_t bytes) -> void* {
        void* p = ws + off;
        off += (bytes + 255) & ~(size_t)255;
        return p;
    };
    float* p_h      = (float*)alloc((size_t)N_ENT * 4 * 4);
    float* p_t      = (float*)alloc((size_t)N_ENT * 4 * 4);
    float* p_r      = (float*)alloc((size_t)N_REL * 4 * 4);
    float* esc      = (float*)alloc((size_t)N_EDGE * 4 * 4);
    float* denom    = (float*)alloc((size_t)N_ENT * 4 * 4);
    int*   counts   = (int*)alloc((size_t)N_ENT * 4);
    int*   row_start= (int*)alloc(((size_t)N_ENT + 1) * 4);
    int*   cursor   = (int*)alloc((size_t)N_ENT * 4);
    int*   csr_col  = (int*)alloc((size_t)N_EDGE * 4);
    float* csr_a    = (float*)alloc((size_t)N_EDGE * 4 * 4);
    float* Za       = (float*)alloc((size_t)N_ENT * 256 * 4);
    float* Zb       = (float*)alloc((size_t)N_ENT * 256 * 4);

    hipMemsetAsync(denom,  0, (size_t)N_ENT * 4 * 4, stream);
    hipMemsetAsync(counts, 0, (size_t)N_ENT * 4, stream);
    hipMemsetAsync(cursor, 0, (size_t)N_ENT * 4, stream);

    proj_kernel<<<(N_ENT + 63) / 64, 256, 0, stream>>>(entity, W_h, att_h, p_h, N_ENT);
    proj_kernel<<<(N_ENT + 63) / 64, 256, 0, stream>>>(entity, W_t, att_t, p_t, N_ENT);
    proj_kernel<<<(N_REL + 63) / 64, 256, 0, stream>>>(rel,    W_r, att_r, p_r, N_REL);

    edge_score_kernel<<<(N_EDGE + 255) / 256, 256, 0, stream>>>(
        eidx, etype, p_h, p_t, p_r, esc, denom, counts);

    scan_kernel<<<1, 1024, 0, stream>>>(counts, row_start);
    scatter_kernel<<<(N_EDGE + 255) / 256, 256, 0, stream>>>(
        eidx, esc, denom, row_start, cursor, csr_col, csr_a);

    // power iteration: Z1..Z5 (first step reads emb broadcast directly)
    spmm_kernel<true ><<<N_ENT / 4, 256, 0, stream>>>(nullptr, entity, row_start, csr_col, csr_a, Zb);
    spmm_kernel<false><<<N_ENT / 4, 256, 0, stream>>>(Zb, entity, row_start, csr_col, csr_a, Za);
    spmm_kernel<false><<<N_ENT / 4, 256, 0, stream>>>(Za, entity, row_start, csr_col, csr_a, Zb);
    spmm_kernel<false><<<N_ENT / 4, 256, 0, stream>>>(Zb, entity, row_start, csr_col, csr_a, Za);
    spmm_kernel<false><<<N_ENT / 4, 256, 0, stream>>>(Za, entity, row_start, csr_col, csr_a, Zb);

    outproj_kernel<<<(N_ENT + 63) / 64, 256, 0, stream>>>(Zb, W_o, out);
}

// Round 3
// 871.415 us; speedup vs baseline: 1.6086x; 1.1618x over previous
//
#include <hip/hip_runtime.h>
#include <math.h>

#define N_ENT 100000
#define N_EDGE 500000
#define N_REL 200
// DIM=64, HEADS=4, HD=256

__device__ __forceinline__ float fast_tanh(float x) {
    float xc = fminf(x, 15.f);
    float e = __expf(2.f * xc);
    return (e - 1.f) / (e + 1.f);
}

// ---------------------------------------------------------------------------
// p[n,h] = sum_d tanh( (embed[n,:] @ W)[h*64+d] ) * att[h,d]
__global__ __launch_bounds__(256) void proj_kernel(
    const float* __restrict__ embed,   // [nrows,64]
    const float* __restrict__ W,       // [64,256]
    const float* __restrict__ att,     // [4,64]
    float* __restrict__ p,             // [nrows,4]
    int nrows)
{
    __shared__ float e_lds[64][64];
    const int h = threadIdx.x >> 6;
    const int d = threadIdx.x & 63;
    const int base = blockIdx.x * 64;

    float wcol[64];
#pragma unroll
    for (int k = 0; k < 64; ++k)
        wcol[k] = W[k * 256 + h * 64 + d];
    const float attv = att[h * 64 + d];

    const int tile = min(64, nrows - base);
    for (int idx = threadIdx.x; idx < tile * 64; idx += 256)
        e_lds[idx >> 6][idx & 63] = embed[(size_t)base * 64 + idx];
    __syncthreads();

    for (int i = 0; i < tile; ++i) {
        float dot = 0.f;
#pragma unroll
        for (int k = 0; k < 64; ++k)
            dot = fmaf(e_lds[i][k], wcol[k], dot);
        float v = fast_tanh(dot) * attv;
#pragma unroll
        for (int off = 32; off > 0; off >>= 1)
            v += __shfl_down(v, off, 64);
        if (d == 0) p[(size_t)(base + i) * 4 + h] = v;
    }
}

// ---------------------------------------------------------------------------
__global__ __launch_bounds__(256) void edge_score_kernel(
    const int* __restrict__ eidx,      // [2,E] row0=head row1=tail
    const int* __restrict__ etype,     // [E]
    const float* __restrict__ ph, const float* __restrict__ pt,
    const float* __restrict__ pr,
    float* __restrict__ esc,           // [E,4]
    float* __restrict__ denom,         // [N,4]
    int* __restrict__ counts)          // [N]
{
    int e = blockIdx.x * 256 + threadIdx.x;
    if (e >= N_EDGE) return;
    int hn = eidx[e];
    int tn = eidx[N_EDGE + e];
    int r  = etype[e];
    float4 a = *(const float4*)(ph + (size_t)hn * 4);
    float4 b = *(const float4*)(pt + (size_t)tn * 4);
    float4 c = *(const float4*)(pr + (size_t)r * 4);
    float s0 = a.x + b.x + c.x;
    float s1 = a.y + b.y + c.y;
    float s2 = a.z + b.z + c.z;
    float s3 = a.w + b.w + c.w;
    s0 = s0 >= 0.f ? s0 : 0.01f * s0;
    s1 = s1 >= 0.f ? s1 : 0.01f * s1;
    s2 = s2 >= 0.f ? s2 : 0.01f * s2;
    s3 = s3 >= 0.f ? s3 : 0.01f * s3;
    float e0 = __expf(s0), e1 = __expf(s1), e2 = __expf(s2), e3 = __expf(s3);
    *(float4*)(esc + (size_t)e * 4) = make_float4(e0, e1, e2, e3);
    atomicAdd(&denom[(size_t)hn * 4 + 0], e0);
    atomicAdd(&denom[(size_t)hn * 4 + 1], e1);
    atomicAdd(&denom[(size_t)hn * 4 + 2], e2);
    atomicAdd(&denom[(size_t)hn * 4 + 3], e3);
    atomicAdd(&counts[hn], 1);
}

// ---------------------------------------------------------------------------
// Exclusive scan of counts[N_ENT] -> row_start[N_ENT+1]. Single block.
__global__ __launch_bounds__(1024) void scan_kernel(
    const int* __restrict__ counts, int* __restrict__ row_start)
{
    __shared__ int wsum[16];
    __shared__ int carry_s;
    const int lane = threadIdx.x & 63;
    const int wid  = threadIdx.x >> 6;
    if (threadIdx.x == 0) carry_s = 0;
    __syncthreads();
    for (int base = 0; base < N_ENT; base += 4096) {
        int i0 = base + (int)threadIdx.x * 4;
        int4 v = make_int4(0, 0, 0, 0);
        if (i0 + 3 < N_ENT) v = *(const int4*)(counts + i0);
        else {
            if (i0 + 0 < N_ENT) v.x = counts[i0 + 0];
            if (i0 + 1 < N_ENT) v.y = counts[i0 + 1];
            if (i0 + 2 < N_ENT) v.z = counts[i0 + 2];
            if (i0 + 3 < N_ENT) v.w = counts[i0 + 3];
        }
        int s1 = v.x + v.y, s2 = s1 + v.z, tsum = s2 + v.w;
        int incl = tsum;
#pragma unroll
        for (int off = 1; off < 64; off <<= 1) {
            int t = __shfl_up(incl, off, 64);
            if (lane >= off) incl += t;
        }
        if (lane == 63) wsum[wid] = incl;
        __syncthreads();                              // A
        int wave_off = 0;
#pragma unroll
        for (int w = 0; w < 16; ++w)
            wave_off += (w < wid) ? wsum[w] : 0;
        int carry = carry_s;
        int excl = carry + wave_off + (incl - tsum);
        if (i0 + 3 < N_ENT) {
            *(int4*)(row_start + i0) = make_int4(excl, excl + v.x, excl + s1, excl + s2);
        } else {
            if (i0 + 0 < N_ENT) row_start[i0 + 0] = excl;
            if (i0 + 1 < N_ENT) row_start[i0 + 1] = excl + v.x;
            if (i0 + 2 < N_ENT) row_start[i0 + 2] = excl + s1;
            if (i0 + 3 < N_ENT) row_start[i0 + 3] = excl + s2;
        }
        __syncthreads();                              // B
        if (threadIdx.x == 1023) carry_s = carry + wave_off + incl;
    }
    __syncthreads();
    if (threadIdx.x == 0) row_start[N_ENT] = carry_s;
}

// ---------------------------------------------------------------------------
__global__ __launch_bounds__(256) void scatter_kernel(
    const int* __restrict__ eidx,
    const float* __restrict__ esc, const float* __restrict__ denom,
    const int* __restrict__ row_start, int* __restrict__ cursor,
    int* __restrict__ csr_col, float* __restrict__ csr_a)
{
    int e = blockIdx.x * 256 + threadIdx.x;
    if (e >= N_EDGE) return;
    int hn = eidx[e];
    int tn = eidx[N_EDGE + e];
    float4 ev = *(const float4*)(esc + (size_t)e * 4);
    float4 dn = *(const float4*)(denom + (size_t)hn * 4);
    float4 a;
    a.x = 0.9f * ev.x / (dn.x + 1e-16f);
    a.y = 0.9f * ev.y / (dn.y + 1e-16f);
    a.z = 0.9f * ev.z / (dn.z + 1e-16f);
    a.w = 0.9f * ev.w / (dn.w + 1e-16f);
    int pos = row_start[hn] + atomicAdd(&cursor[hn], 1);
    csr_col[pos] = tn;
    *(float4*)(csr_a + (size_t)pos * 4) = a;
}

// ---------------------------------------------------------------------------
// SpMM step. Wave per entity; lane handles float4, h = lane/16.
// Metadata for 16 edges fetched with 2 lane-parallel loads, distributed
// via shfl; gathers issued 4 at a time into independent accumulators.
template <bool FIRST>
__global__ __launch_bounds__(256) void spmm_kernel(
    const float* __restrict__ Zin, const float* __restrict__ emb,
    const int* __restrict__ row_start, const int* __restrict__ csr_col,
    const float* __restrict__ csr_a, float* __restrict__ Zout)
{
    const int wave = threadIdx.x >> 6;
    const int lane = threadIdx.x & 63;
    const int n = blockIdx.x * 4 + wave;
    const int h = lane >> 4;

    const float4* e4 = (const float4*)emb;   // [N][16]
    float4 zi = e4[(size_t)n * 16 + (lane & 15)];
    float4 acc0 = make_float4(0.1f * zi.x, 0.1f * zi.y, 0.1f * zi.z, 0.1f * zi.w);
    float4 acc1 = make_float4(0.f, 0.f, 0.f, 0.f);
    float4 acc2 = make_float4(0.f, 0.f, 0.f, 0.f);
    float4 acc3 = make_float4(0.f, 0.f, 0.f, 0.f);

    const int s   = row_start[n];
    const int end = row_start[n + 1];

    auto zrow = [&](int c) -> float4 {
        if (FIRST)
            return *(const float4*)(emb + (size_t)c * 64 + 4 * (lane & 15));
        else
            return *(const float4*)(Zin + (size_t)c * 256 + 4 * lane);
    };
    auto fma4 = [](float4& acc, float a, const float4& z) {
        acc.x = fmaf(a, z.x, acc.x);
        acc.y = fmaf(a, z.y, acc.y);
        acc.z = fmaf(a, z.z, acc.z);
        acc.w = fmaf(a, z.w, acc.w);
    };

    for (int b = s; b < end; b += 16) {
        const int nb = min(16, end - b);
        // lane-parallel metadata fetch: 16 cols, 64 attn values
        int   cl = (lane < nb) ? csr_col[b + lane] : 0;
        float al = (lane < nb * 4) ? csr_a[(size_t)b * 4 + lane] : 0.f;

        int j = 0;
        for (; j + 4 <= nb; j += 4) {
            int c0 = __shfl(cl, j + 0, 64);
            int c1 = __shfl(cl, j + 1, 64);
            int c2 = __shfl(cl, j + 2, 64);
            int c3 = __shfl(cl, j + 3, 64);
            float a0 = __shfl(al, (j + 0) * 4 + h, 64);
            float a1 = __shfl(al, (j + 1) * 4 + h, 64);
            float a2 = __shfl(al, (j + 2) * 4 + h, 64);
            float a3 = __shfl(al, (j + 3) * 4 + h, 64);
            float4 za = zrow(c0);
            float4 zb = zrow(c1);
            float4 zc = zrow(c2);
            float4 zd = zrow(c3);
            fma4(acc0, a0, za);
            fma4(acc1, a1, zb);
            fma4(acc2, a2, zc);
            fma4(acc3, a3, zd);
        }
        // remainder (0-3 edges), independent accumulators
        if (j + 0 < nb) {
            int c = __shfl(cl, j + 0, 64);
            float a = __shfl(al, (j + 0) * 4 + h, 64);
            float4 z = zrow(c);
            fma4(acc0, a, z);
        }
        if (j + 1 < nb) {
            int c = __shfl(cl, j + 1, 64);
            float a = __shfl(al, (j + 1) * 4 + h, 64);
            float4 z = zrow(c);
            fma4(acc1, a, z);
        }
        if (j + 2 < nb) {
            int c = __shfl(cl, j + 2, 64);
            float a = __shfl(al, (j + 2) * 4 + h, 64);
            float4 z = zrow(c);
            fma4(acc2, a, z);
        }
    }
    acc0.x += acc1.x + acc2.x + acc3.x;
    acc0.y += acc1.y + acc2.y + acc3.y;
    acc0.z += acc1.z + acc2.z + acc3.z;
    acc0.w += acc1.w + acc2.w + acc3.w;
    *(float4*)(Zout + (size_t)n * 256 + 4 * lane) = acc0;
}

// ---------------------------------------------------------------------------
// out[100000,64] = Z[100000,256] @ Wo[256,64].
// Block: 64 entities. K processed in 4 chunks of 64: Z chunk + Wo chunk
// staged in LDS (~34 KB total -> 4 blocks/CU). Thread: 4 ent x 4 dim tile.
__global__ __launch_bounds__(256) void outproj_kernel(
    const float* __restrict__ Z, const float* __restrict__ Wo,
    float* __restrict__ out)
{
    __shared__ float z_lds[64][68];   // 64 ents x 64 k (pad->68: 2-way max)
    __shared__ float w_lds[64][64];   // 64 k x 64 d
    const int t = threadIdx.x;
    const int base = blockIdx.x * 64;
    const int er = t & 15;
    const int d0 = (t >> 4) * 4;

    float acc[4][4] = {};
    for (int kc = 0; kc < 4; ++kc) {
        // stage Wo chunk (16 KB): rows kc*64..+63
        {
            const float4* src = (const float4*)(Wo + (size_t)kc * 64 * 64);
            float4* dst = (float4*)&w_lds[0][0];
#pragma unroll
            for (int i = 0; i < 4; ++i)
                dst[t + 256 * i] = src[t + 256 * i];
        }
        // stage Z chunk (16 KB): 64 ents x cols [kc*64, kc*64+64), coalesced
        {
#pragma unroll
            for (int i = 0; i < 4; ++i) {
                int f = t + 256 * i;           // 0..1023
                int row = f >> 4, c4 = f & 15;
                int gr = min(base + row, N_ENT - 1);
                float4 v = *(const float4*)(Z + (size_t)gr * 256 + kc * 64 + 4 * c4);
                *(float4*)&z_lds[row][4 * c4] = v;
            }
        }
        __syncthreads();

        for (int k4 = 0; k4 < 16; ++k4) {
            float4 z0 = *(const float4*)&z_lds[er +  0][4 * k4];
            float4 z1 = *(const float4*)&z_lds[er + 16][4 * k4];
            float4 z2 = *(const float4*)&z_lds[er + 32][4 * k4];
            float4 z3 = *(const float4*)&z_lds[er + 48][4 * k4];
#pragma unroll
            for (int jj = 0; jj < 4; ++jj) {
                float4 wv = *(const float4*)&w_lds[4 * k4 + jj][d0];
                float zj0 = ((const float*)&z0)[jj];
                float zj1 = ((const float*)&z1)[jj];
                float zj2 = ((const float*)&z2)[jj];
                float zj3 = ((const float*)&z3)[jj];
                acc[0][0] = fmaf(zj0, wv.x, acc[0][0]);
                acc[0][1] = fmaf(zj0, wv.y, acc[0][1]);
                acc[0][2] = fmaf(zj0, wv.z, acc[0][2]);
                acc[0][3] = fmaf(zj0, wv.w, acc[0][3]);
                acc[1][0] = fmaf(zj1, wv.x, acc[1][0]);
                acc[1][1] = fmaf(zj1, wv.y, acc[1][1]);
                acc[1][2] = fmaf(zj1, wv.z, acc[1][2]);
                acc[1][3] = fmaf(zj1, wv.w, acc[1][3]);
                acc[2][0] = fmaf(zj2, wv.x, acc[2][0]);
                acc[2][1] = fmaf(zj2, wv.y, acc[2][1]);
                acc[2][2] = fmaf(zj2, wv.z, acc[2][2]);
                acc[2][3] = fmaf(zj2, wv.w, acc[2][3]);
                acc[3][0] = fmaf(zj3, wv.x, acc[3][0]);
                acc[3][1] = fmaf(zj3, wv.y, acc[3][1]);
                acc[3][2] = fmaf(zj3, wv.z, acc[3][2]);
                acc[3][3] = fmaf(zj3, wv.w, acc[3][3]);
            }
        }
        __syncthreads();
    }

#pragma unroll
    for (int i = 0; i < 4; ++i) {
        int row = base + er + 16 * i;
        if (row < N_ENT) {
            *(float4*)(out + (size_t)row * 64 + d0) =
                make_float4(acc[i][0], acc[i][1], acc[i][2], acc[i][3]);
        }
    }
}

// ---------------------------------------------------------------------------
extern "C" void kernel_launch(void* const* d_in, const int* in_sizes, int n_in,
                              void* d_out, int out_size, void* d_ws, size_t ws_size,
                              hipStream_t stream)
{
    const float* entity = (const float*)d_in[0];
    const float* rel    = (const float*)d_in[1];
    const float* W_h    = (const float*)d_in[2];
    const float* W_t    = (const float*)d_in[3];
    const float* W_r    = (const float*)d_in[4];
    const float* att_h  = (const float*)d_in[5];
    const float* att_t  = (const float*)d_in[6];
    const float* att_r  = (const float*)d_in[7];
    const float* W_o    = (const float*)d_in[8];
    const int*   eidx   = (const int*)d_in[9];   // [2,E]
    const int*   etype  = (const int*)d_in[10];  // [E]
    float* out = (float*)d_out;

    char* ws = (char*)d_ws;
    size_t off = 0;
    auto alloc = [&](size_t bytes) -> void* {
        void* p = ws + off;
        off += (bytes + 255) & ~(size_t)255;
        return p;
    };
    float* p_h      = (float*)alloc((size_t)N_ENT * 4 * 4);
    float* p_t      = (float*)alloc((size_t)N_ENT * 4 * 4);
    float* p_r      = (float*)alloc((size_t)N_REL * 4 * 4);
    float* esc      = (float*)alloc((size_t)N_EDGE * 4 * 4);
    float* denom    = (float*)alloc((size_t)N_ENT * 4 * 4);
    int*   counts   = (int*)alloc((size_t)N_ENT * 4);
    int*   row_start= (int*)alloc(((size_t)N_ENT + 1) * 4);
    int*   cursor   = (int*)alloc((size_t)N_ENT * 4);
    int*   csr_col  = (int*)alloc((size_t)N_EDGE * 4);
    float* csr_a    = (float*)alloc((size_t)N_EDGE * 4 * 4);
    float* Za       = (float*)alloc((size_t)N_ENT * 256 * 4);
    float* Zb       = (float*)alloc((size_t)N_ENT * 256 * 4);

    hipMemsetAsync(denom,  0, (size_t)N_ENT * 4 * 4, stream);
    hipMemsetAsync(counts, 0, (size_t)N_ENT * 4, stream);
    hipMemsetAsync(cursor, 0, (size_t)N_ENT * 4, stream);

    proj_kernel<<<(N_ENT + 63) / 64, 256, 0, stream>>>(entity, W_h, att_h, p_h, N_ENT);
    proj_kernel<<<(N_ENT + 63) / 64, 256, 0, stream>>>(entity, W_t, att_t, p_t, N_ENT);
    proj_kernel<<<(N_REL + 63) / 64, 256, 0, stream>>>(rel,    W_r, att_r, p_r, N_REL);

    edge_score_kernel<<<(N_EDGE + 255) / 256, 256, 0, stream>>>(
        eidx, etype, p_h, p_t, p_r, esc, denom, counts);

    scan_kernel<<<1, 1024, 0, stream>>>(counts, row_start);
    scatter_kernel<<<(N_EDGE + 255) / 256, 256, 0, stream>>>(
        eidx, esc, denom, row_start, cursor, csr_col, csr_a);

    // power iteration: Z1..Z5 (first step reads emb broadcast directly)
    spmm_kernel<true ><<<N_ENT / 4, 256, 0, stream>>>(nullptr, entity, row_start, csr_col, csr_a, Zb);
    spmm_kernel<false><<<N_ENT / 4, 256, 0, stream>>>(Zb, entity, row_start, csr_col, csr_a, Za);
    spmm_kernel<false><<<N_ENT / 4, 256, 0, stream>>>(Za, entity, row_start, csr_col, csr_a, Zb);
    spmm_kernel<false><<<N_ENT / 4, 256, 0, stream>>>(Zb, entity, row_start, csr_col, csr_a, Za);
    spmm_kernel<false><<<N_ENT / 4, 256, 0, stream>>>(Za, entity, row_start, csr_col, csr_a, Zb);

    outproj_kernel<<<(N_ENT + 63) / 64, 256, 0, stream>>>(Zb, W_o, out);
}

// Round 4
// 784.318 us; speedup vs baseline: 1.7872x; 1.1110x over previous
//
#include <hip/hip_runtime.h>
#include <math.h>

#define N_ENT 100000
#define N_EDGE 500000
#define N_REL 200
// DIM=64, HEADS=4, HD=256

__device__ __forceinline__ float fast_tanh(float x) {
    float xc = fminf(x, 15.f);
    float e = __expf(2.f * xc);
    return (e - 1.f) / (e + 1.f);
}

// ---------------------------------------------------------------------------
// p[n,h] = sum_d tanh( (embed[n,:] @ W)[h*64+d] ) * att[h,d]
__global__ __launch_bounds__(256) void proj_kernel(
    const float* __restrict__ embed,   // [nrows,64]
    const float* __restrict__ W,       // [64,256]
    const float* __restrict__ att,     // [4,64]
    float* __restrict__ p,             // [nrows,4]
    int nrows)
{
    __shared__ float e_lds[64][64];
    const int h = threadIdx.x >> 6;
    const int d = threadIdx.x & 63;
    const int base = blockIdx.x * 64;

    float wcol[64];
#pragma unroll
    for (int k = 0; k < 64; ++k)
        wcol[k] = W[k * 256 + h * 64 + d];
    const float attv = att[h * 64 + d];

    const int tile = min(64, nrows - base);
    for (int idx = threadIdx.x; idx < tile * 64; idx += 256)
        e_lds[idx >> 6][idx & 63] = embed[(size_t)base * 64 + idx];
    __syncthreads();

    for (int i = 0; i < tile; ++i) {
        float dot = 0.f;
#pragma unroll
        for (int k = 0; k < 64; ++k)
            dot = fmaf(e_lds[i][k], wcol[k], dot);
        float v = fast_tanh(dot) * attv;
#pragma unroll
        for (int off = 32; off > 0; off >>= 1)
            v += __shfl_down(v, off, 64);
        if (d == 0) p[(size_t)(base + i) * 4 + h] = v;
    }
}

// ---------------------------------------------------------------------------
// Degree histogram: 1 atomic per edge.
__global__ __launch_bounds__(256) void hist_kernel(
    const int* __restrict__ eidx, int* __restrict__ counts)
{
    int e = blockIdx.x * 256 + threadIdx.x;
    if (e >= N_EDGE) return;
    atomicAdd(&counts[eidx[e]], 1);
}

// ---------------------------------------------------------------------------
// Exclusive scan of counts[N_ENT] -> row_start[N_ENT+1]. Single block.
__global__ __launch_bounds__(1024) void scan_kernel(
    const int* __restrict__ counts, int* __restrict__ row_start)
{
    __shared__ int wsum[16];
    __shared__ int carry_s;
    const int lane = threadIdx.x & 63;
    const int wid  = threadIdx.x >> 6;
    if (threadIdx.x == 0) carry_s = 0;
    __syncthreads();
    for (int base = 0; base < N_ENT; base += 4096) {
        int i0 = base + (int)threadIdx.x * 4;
        int4 v = make_int4(0, 0, 0, 0);
        if (i0 + 3 < N_ENT) v = *(const int4*)(counts + i0);
        else {
            if (i0 + 0 < N_ENT) v.x = counts[i0 + 0];
            if (i0 + 1 < N_ENT) v.y = counts[i0 + 1];
            if (i0 + 2 < N_ENT) v.z = counts[i0 + 2];
            if (i0 + 3 < N_ENT) v.w = counts[i0 + 3];
        }
        int s1 = v.x + v.y, s2 = s1 + v.z, tsum = s2 + v.w;
        int incl = tsum;
#pragma unroll
        for (int off = 1; off < 64; off <<= 1) {
            int t = __shfl_up(incl, off, 64);
            if (lane >= off) incl += t;
        }
        if (lane == 63) wsum[wid] = incl;
        __syncthreads();                              // A
        int wave_off = 0;
#pragma unroll
        for (int w = 0; w < 16; ++w)
            wave_off += (w < wid) ? wsum[w] : 0;
        int carry = carry_s;
        int excl = carry + wave_off + (incl - tsum);
        if (i0 + 3 < N_ENT) {
            *(int4*)(row_start + i0) = make_int4(excl, excl + v.x, excl + s1, excl + s2);
        } else {
            if (i0 + 0 < N_ENT) row_start[i0 + 0] = excl;
            if (i0 + 1 < N_ENT) row_start[i0 + 1] = excl + v.x;
            if (i0 + 2 < N_ENT) row_start[i0 + 2] = excl + s1;
            if (i0 + 3 < N_ENT) row_start[i0 + 3] = excl + s2;
        }
        __syncthreads();                              // B
        if (threadIdx.x == 1023) carry_s = carry + wave_off + incl;
    }
    __syncthreads();
    if (threadIdx.x == 0) row_start[N_ENT] = carry_s;
}

// ---------------------------------------------------------------------------
// Per-edge: compute exp(leaky(score)) directly and scatter RAW exp into CSR.
__global__ __launch_bounds__(256) void scatter_score_kernel(
    const int* __restrict__ eidx, const int* __restrict__ etype,
    const float* __restrict__ ph, const float* __restrict__ pt,
    const float* __restrict__ pr,
    const int* __restrict__ row_start, int* __restrict__ cursor,
    int* __restrict__ csr_col, float* __restrict__ csr_a)
{
    int e = blockIdx.x * 256 + threadIdx.x;
    if (e >= N_EDGE) return;
    int hn = eidx[e];
    int tn = eidx[N_EDGE + e];
    int r  = etype[e];
    float4 a = *(const float4*)(ph + (size_t)hn * 4);
    float4 b = *(const float4*)(pt + (size_t)tn * 4);
    float4 c = *(const float4*)(pr + (size_t)r * 4);
    float s0 = a.x + b.x + c.x;
    float s1 = a.y + b.y + c.y;
    float s2 = a.z + b.z + c.z;
    float s3 = a.w + b.w + c.w;
    s0 = s0 >= 0.f ? s0 : 0.01f * s0;
    s1 = s1 >= 0.f ? s1 : 0.01f * s1;
    s2 = s2 >= 0.f ? s2 : 0.01f * s2;
    s3 = s3 >= 0.f ? s3 : 0.01f * s3;
    float4 ev = make_float4(__expf(s0), __expf(s1), __expf(s2), __expf(s3));
    int pos = row_start[hn] + atomicAdd(&cursor[hn], 1);
    csr_col[pos] = tn;
    *(float4*)(csr_a + (size_t)pos * 4) = ev;
}

// ---------------------------------------------------------------------------
// Row-wise softmax normalize: csr_a[p][h] *= 0.9 / (sum_row csr_a[.][h] + eps)
// Wave per row; lane = (entry, component): p = s + lane/4, comp = lane&3.
__global__ __launch_bounds__(256) void normalize_kernel(
    const int* __restrict__ row_start, float* __restrict__ csr_a)
{
    const int wid  = threadIdx.x >> 6;
    const int lane = threadIdx.x & 63;
    const int n = blockIdx.x * 4 + wid;
    if (n >= N_ENT) return;
    const int s   = row_start[n];
    const int end = row_start[n + 1];
    const int nf  = (end - s) * 4;          // floats in this row

    float sum = 0.f;
    for (int f = lane; f < nf; f += 64)
        sum += csr_a[(size_t)s * 4 + f];
    // reduce over lanes with equal (lane&3)
#pragma unroll
    for (int off = 4; off < 64; off <<= 1)
        sum += __shfl_xor(sum, off, 64);
    float scale = 0.9f / (sum + 1e-16f);
    for (int f = lane; f < nf; f += 64)
        csr_a[(size_t)s * 4 + f] *= scale;
}

// ---------------------------------------------------------------------------
// SpMM step. Wave per entity; lane handles float4, h = lane/16.
template <bool FIRST>
__global__ __launch_bounds__(256) void spmm_kernel(
    const float* __restrict__ Zin, const float* __restrict__ emb,
    const int* __restrict__ row_start, const int* __restrict__ csr_col,
    const float* __restrict__ csr_a, float* __restrict__ Zout)
{
    const int wave = threadIdx.x >> 6;
    const int lane = threadIdx.x & 63;
    const int n = blockIdx.x * 4 + wave;
    const int h = lane >> 4;

    const float4* e4 = (const float4*)emb;   // [N][16]
    float4 zi = e4[(size_t)n * 16 + (lane & 15)];
    float4 acc0 = make_float4(0.1f * zi.x, 0.1f * zi.y, 0.1f * zi.z, 0.1f * zi.w);
    float4 acc1 = make_float4(0.f, 0.f, 0.f, 0.f);
    float4 acc2 = make_float4(0.f, 0.f, 0.f, 0.f);
    float4 acc3 = make_float4(0.f, 0.f, 0.f, 0.f);

    const int s   = row_start[n];
    const int end = row_start[n + 1];

    auto zrow = [&](int c) -> float4 {
        if (FIRST)
            return *(const float4*)(emb + (size_t)c * 64 + 4 * (lane & 15));
        else
            return *(const float4*)(Zin + (size_t)c * 256 + 4 * lane);
    };
    auto fma4 = [](float4& acc, float a, const float4& z) {
        acc.x = fmaf(a, z.x, acc.x);
        acc.y = fmaf(a, z.y, acc.y);
        acc.z = fmaf(a, z.z, acc.z);
        acc.w = fmaf(a, z.w, acc.w);
    };

    for (int b = s; b < end; b += 16) {
        const int nb = min(16, end - b);
        int   cl = (lane < nb) ? csr_col[b + lane] : 0;
        float al = (lane < nb * 4) ? csr_a[(size_t)b * 4 + lane] : 0.f;

        int j = 0;
        for (; j + 4 <= nb; j += 4) {
            int c0 = __shfl(cl, j + 0, 64);
            int c1 = __shfl(cl, j + 1, 64);
            int c2 = __shfl(cl, j + 2, 64);
            int c3 = __shfl(cl, j + 3, 64);
            float a0 = __shfl(al, (j + 0) * 4 + h, 64);
            float a1 = __shfl(al, (j + 1) * 4 + h, 64);
            float a2 = __shfl(al, (j + 2) * 4 + h, 64);
            float a3 = __shfl(al, (j + 3) * 4 + h, 64);
            float4 za = zrow(c0);
            float4 zb = zrow(c1);
            float4 zc = zrow(c2);
            float4 zd = zrow(c3);
            fma4(acc0, a0, za);
            fma4(acc1, a1, zb);
            fma4(acc2, a2, zc);
            fma4(acc3, a3, zd);
        }
        if (j + 0 < nb) {
            int c = __shfl(cl, j + 0, 64);
            float a = __shfl(al, (j + 0) * 4 + h, 64);
            float4 z = zrow(c);
            fma4(acc0, a, z);
        }
        if (j + 1 < nb) {
            int c = __shfl(cl, j + 1, 64);
            float a = __shfl(al, (j + 1) * 4 + h, 64);
            float4 z = zrow(c);
            fma4(acc1, a, z);
        }
        if (j + 2 < nb) {
            int c = __shfl(cl, j + 2, 64);
            float a = __shfl(al, (j + 2) * 4 + h, 64);
            float4 z = zrow(c);
            fma4(acc2, a, z);
        }
    }
    acc0.x += acc1.x + acc2.x + acc3.x;
    acc0.y += acc1.y + acc2.y + acc3.y;
    acc0.z += acc1.z + acc2.z + acc3.z;
    acc0.w += acc1.w + acc2.w + acc3.w;
    *(float4*)(Zout + (size_t)n * 256 + 4 * lane) = acc0;
}

// ---------------------------------------------------------------------------
// out[100000,64] = Z[100000,256] @ Wo[256,64]. K in 4 chunks of 64 via LDS.
__global__ __launch_bounds__(256) void outproj_kernel(
    const float* __restrict__ Z, const float* __restrict__ Wo,
    float* __restrict__ out)
{
    __shared__ float z_lds[64][68];
    __shared__ float w_lds[64][64];
    const int t = threadIdx.x;
    const int base = blockIdx.x * 64;
    const int er = t & 15;
    const int d0 = (t >> 4) * 4;

    float acc[4][4] = {};
    for (int kc = 0; kc < 4; ++kc) {
        {
            const float4* src = (const float4*)(Wo + (size_t)kc * 64 * 64);
            float4* dst = (float4*)&w_lds[0][0];
#pragma unroll
            for (int i = 0; i < 4; ++i)
                dst[t + 256 * i] = src[t + 256 * i];
        }
        {
#pragma unroll
            for (int i = 0; i < 4; ++i) {
                int f = t + 256 * i;
                int row = f >> 4, c4 = f & 15;
                int gr = min(base + row, N_ENT - 1);
                float4 v = *(const float4*)(Z + (size_t)gr * 256 + kc * 64 + 4 * c4);
                *(float4*)&z_lds[row][4 * c4] = v;
            }
        }
        __syncthreads();

        for (int k4 = 0; k4 < 16; ++k4) {
            float4 z0 = *(const float4*)&z_lds[er +  0][4 * k4];
            float4 z1 = *(const float4*)&z_lds[er + 16][4 * k4];
            float4 z2 = *(const float4*)&z_lds[er + 32][4 * k4];
            float4 z3 = *(const float4*)&z_lds[er + 48][4 * k4];
#pragma unroll
            for (int jj = 0; jj < 4; ++jj) {
                float4 wv = *(const float4*)&w_lds[4 * k4 + jj][d0];
                float zj0 = ((const float*)&z0)[jj];
                float zj1 = ((const float*)&z1)[jj];
                float zj2 = ((const float*)&z2)[jj];
                float zj3 = ((const float*)&z3)[jj];
                acc[0][0] = fmaf(zj0, wv.x, acc[0][0]);
                acc[0][1] = fmaf(zj0, wv.y, acc[0][1]);
                acc[0][2] = fmaf(zj0, wv.z, acc[0][2]);
                acc[0][3] = fmaf(zj0, wv.w, acc[0][3]);
                acc[1][0] = fmaf(zj1, wv.x, acc[1][0]);
                acc[1][1] = fmaf(zj1, wv.y, acc[1][1]);
                acc[1][2] = fmaf(zj1, wv.z, acc[1][2]);
                acc[1][3] = fmaf(zj1, wv.w, acc[1][3]);
                acc[2][0] = fmaf(zj2, wv.x, acc[2][0]);
                acc[2][1] = fmaf(zj2, wv.y, acc[2][1]);
                acc[2][2] = fmaf(zj2, wv.z, acc[2][2]);
                acc[2][3] = fmaf(zj2, wv.w, acc[2][3]);
                acc[3][0] = fmaf(zj3, wv.x, acc[3][0]);
                acc[3][1] = fmaf(zj3, wv.y, acc[3][1]);
                acc[3][2] = fmaf(zj3, wv.z, acc[3][2]);
                acc[3][3] = fmaf(zj3, wv.w, acc[3][3]);
            }
        }
        __syncthreads();
    }

#pragma unroll
    for (int i = 0; i < 4; ++i) {
        int row = base + er + 16 * i;
        if (row < N_ENT) {
            *(float4*)(out + (size_t)row * 64 + d0) =
                make_float4(acc[i][0], acc[i][1], acc[i][2], acc[i][3]);
        }
    }
}

// ---------------------------------------------------------------------------
extern "C" void kernel_launch(void* const* d_in, const int* in_sizes, int n_in,
                              void* d_out, int out_size, void* d_ws, size_t ws_size,
                              hipStream_t stream)
{
    const float* entity = (const float*)d_in[0];
    const float* rel    = (const float*)d_in[1];
    const float* W_h    = (const float*)d_in[2];
    const float* W_t    = (const float*)d_in[3];
    const float* W_r    = (const float*)d_in[4];
    const float* att_h  = (const float*)d_in[5];
    const float* att_t  = (const float*)d_in[6];
    const float* att_r  = (const float*)d_in[7];
    const float* W_o    = (const float*)d_in[8];
    const int*   eidx   = (const int*)d_in[9];   // [2,E]
    const int*   etype  = (const int*)d_in[10];  // [E]
    float* out = (float*)d_out;

    char* ws = (char*)d_ws;
    size_t off = 0;
    auto alloc = [&](size_t bytes) -> void* {
        void* p = ws + off;
        off += (bytes + 255) & ~(size_t)255;
        return p;
    };
    float* p_h      = (float*)alloc((size_t)N_ENT * 4 * 4);
    float* p_t      = (float*)alloc((size_t)N_ENT * 4 * 4);
    float* p_r      = (float*)alloc((size_t)N_REL * 4 * 4);
    int*   counts   = (int*)alloc((size_t)N_ENT * 4);
    int*   row_start= (int*)alloc(((size_t)N_ENT + 1) * 4);
    int*   cursor   = (int*)alloc((size_t)N_ENT * 4);
    int*   csr_col  = (int*)alloc((size_t)N_EDGE * 4);
    float* csr_a    = (float*)alloc((size_t)N_EDGE * 4 * 4);
    float* Za       = (float*)alloc((size_t)N_ENT * 256 * 4);
    float* Zb       = (float*)alloc((size_t)N_ENT * 256 * 4);

    hipMemsetAsync(counts, 0, (size_t)N_ENT * 4, stream);
    hipMemsetAsync(cursor, 0, (size_t)N_ENT * 4, stream);

    proj_kernel<<<(N_ENT + 63) / 64, 256, 0, stream>>>(entity, W_h, att_h, p_h, N_ENT);
    proj_kernel<<<(N_ENT + 63) / 64, 256, 0, stream>>>(entity, W_t, att_t, p_t, N_ENT);
    proj_kernel<<<(N_REL + 63) / 64, 256, 0, stream>>>(rel,    W_r, att_r, p_r, N_REL);

    hist_kernel<<<(N_EDGE + 255) / 256, 256, 0, stream>>>(eidx, counts);
    scan_kernel<<<1, 1024, 0, stream>>>(counts, row_start);
    scatter_score_kernel<<<(N_EDGE + 255) / 256, 256, 0, stream>>>(
        eidx, etype, p_h, p_t, p_r, row_start, cursor, csr_col, csr_a);
    normalize_kernel<<<(N_ENT + 3) / 4, 256, 0, stream>>>(row_start, csr_a);

    // power iteration: Z1..Z5 (first step reads emb broadcast directly)
    spmm_kernel<true ><<<N_ENT / 4, 256, 0, stream>>>(nullptr, entity, row_start, csr_col, csr_a, Zb);
    spmm_kernel<false><<<N_ENT / 4, 256, 0, stream>>>(Zb, entity, row_start, csr_col, csr_a, Za);
    spmm_kernel<false><<<N_ENT / 4, 256, 0, stream>>>(Za, entity, row_start, csr_col, csr_a, Zb);
    spmm_kernel<false><<<N_ENT / 4, 256, 0, stream>>>(Zb, entity, row_start, csr_col, csr_a, Za);
    spmm_kernel<false><<<N_ENT / 4, 256, 0, stream>>>(Za, entity, row_start, csr_col, csr_a, Zb);

    outproj_kernel<<<(N_ENT + 63) / 64, 256, 0, stream>>>(Zb, W_o, out);
}

// Round 5
// 692.787 us; speedup vs baseline: 2.0234x; 1.1321x over previous
//
#include <hip/hip_runtime.h>
#include <math.h>

#define N_ENT 100000
#define N_EDGE 500000
#define N_REL 200
// DIM=64, HEADS=4, HD=256

__device__ __forceinline__ float fast_tanh(float x) {
    float xc = fminf(x, 15.f);
    float e = __expf(2.f * xc);
    return (e - 1.f) / (e + 1.f);
}

// ---------------------------------------------------------------------------
// Fused attention projection(s): for each mat m (up to 2 sharing the same
// embed): p_m[n,h] = sum_d tanh( (embed[n,:] @ W_m)[h*64+d] ) * att_m[h,d]
// Register-tiled GEMM: block = 64 entities; per (mat,head) stage 64x64 W
// chunk in LDS; thread computes 4ent x 4col tile; tanh after full-K acc;
// reduction over 64 cols via shfl_xor + small LDS.
template <int NMAT>
__global__ __launch_bounds__(256) void proj_gemm_kernel(
    const float* __restrict__ emb,     // [nrows,64]
    const float* __restrict__ W0,      // [64,256]
    const float* __restrict__ att0,    // [4,64]
    float* __restrict__ p0,            // [nrows,4]
    const float* __restrict__ W1,
    const float* __restrict__ att1,
    float* __restrict__ p1,
    int nrows)
{
    __shared__ float e_lds[64][68];
    __shared__ float w_lds[64][64];
    __shared__ float red[4][64];

    const int t    = threadIdx.x;
    const int wv   = t >> 6;
    const int lane = t & 63;
    const int er   = t & 15;
    const int d0   = (t >> 4) * 4;
    const int base = blockIdx.x * 64;

    // stage embed tile (coalesced float4), clamp OOB rows
#pragma unroll
    for (int i = 0; i < 4; ++i) {
        int f = t + 256 * i;              // 0..1023
        int row = f >> 4, c4 = f & 15;
        int gr = min(base + row, nrows - 1);
        float4 v = *(const float4*)(emb + (size_t)gr * 64 + 4 * c4);
        *(float4*)&e_lds[row][4 * c4] = v;
    }
    __syncthreads();

#pragma unroll
    for (int m = 0; m < NMAT; ++m) {
        const float* W   = (m == 0) ? W0 : W1;
        const float* att = (m == 0) ? att0 : att1;
        float* p         = (m == 0) ? p0 : p1;

        for (int head = 0; head < 4; ++head) {
            // stage W chunk: w_lds[k][c] = W[k][head*64+c]
            {
                int k0 = t >> 4, c4 = t & 15;
#pragma unroll
                for (int kk = 0; kk < 4; ++kk) {
                    int k = k0 + 16 * kk;
                    float4 v = *(const float4*)(W + (size_t)k * 256 + head * 64 + 4 * c4);
                    *(float4*)&w_lds[k][4 * c4] = v;
                }
            }
            __syncthreads();

            float acc[4][4] = {};
            for (int k4 = 0; k4 < 16; ++k4) {
                float4 z0 = *(const float4*)&e_lds[er +  0][4 * k4];
                float4 z1 = *(const float4*)&e_lds[er + 16][4 * k4];
                float4 z2 = *(const float4*)&e_lds[er + 32][4 * k4];
                float4 z3 = *(const float4*)&e_lds[er + 48][4 * k4];
#pragma unroll
                for (int jj = 0; jj < 4; ++jj) {
                    float4 wvv = *(const float4*)&w_lds[4 * k4 + jj][d0];
                    float zj0 = ((const float*)&z0)[jj];
                    float zj1 = ((const float*)&z1)[jj];
                    float zj2 = ((const float*)&z2)[jj];
                    float zj3 = ((const float*)&z3)[jj];
                    acc[0][0] = fmaf(zj0, wvv.x, acc[0][0]);
                    acc[0][1] = fmaf(zj0, wvv.y, acc[0][1]);
                    acc[0][2] = fmaf(zj0, wvv.z, acc[0][2]);
                    acc[0][3] = fmaf(zj0, wvv.w, acc[0][3]);
                    acc[1][0] = fmaf(zj1, wvv.x, acc[1][0]);
                    acc[1][1] = fmaf(zj1, wvv.y, acc[1][1]);
                    acc[1][2] = fmaf(zj1, wvv.z, acc[1][2]);
                    acc[1][3] = fmaf(zj1, wvv.w, acc[1][3]);
                    acc[2][0] = fmaf(zj2, wvv.x, acc[2][0]);
                    acc[2][1] = fmaf(zj2, wvv.y, acc[2][1]);
                    acc[2][2] = fmaf(zj2, wvv.z, acc[2][2]);
                    acc[2][3] = fmaf(zj2, wvv.w, acc[2][3]);
                    acc[3][0] = fmaf(zj3, wvv.x, acc[3][0]);
                    acc[3][1] = fmaf(zj3, wvv.y, acc[3][1]);
                    acc[3][2] = fmaf(zj3, wvv.z, acc[3][2]);
                    acc[3][3] = fmaf(zj3, wvv.w, acc[3][3]);
                }
            }

            // tanh + att weighting + partial reduction over this thread's 4 cols
            float4 av = *(const float4*)(att + head * 64 + d0);
            float partial[4];
#pragma unroll
            for (int i = 0; i < 4; ++i) {
                partial[i] = fast_tanh(acc[i][0]) * av.x
                           + fast_tanh(acc[i][1]) * av.y
                           + fast_tanh(acc[i][2]) * av.z
                           + fast_tanh(acc[i][3]) * av.w;
            }
            // in-wave reduce across lanes er, er+16, er+32, er+48
#pragma unroll
            for (int i = 0; i < 4; ++i) {
                partial[i] += __shfl_xor(partial[i], 16, 64);
                partial[i] += __shfl_xor(partial[i], 32, 64);
            }
            if (lane < 16) {
#pragma unroll
                for (int i = 0; i < 4; ++i)
                    red[wv][lane + 16 * i] = partial[i];
            }
            __syncthreads();
            if (t < 64) {
                float sum = red[0][t] + red[1][t] + red[2][t] + red[3][t];
                int row = base + t;
                if (row < nrows) p[(size_t)row * 4 + head] = sum;
            }
            __syncthreads();
        }
    }
}

// ---------------------------------------------------------------------------
// Degree histogram: 1 atomic per edge.
__global__ __launch_bounds__(256) void hist_kernel(
    const int* __restrict__ eidx, int* __restrict__ counts)
{
    int e = blockIdx.x * 256 + threadIdx.x;
    if (e >= N_EDGE) return;
    atomicAdd(&counts[eidx[e]], 1);
}

// ---------------------------------------------------------------------------
// Exclusive scan of counts[N_ENT] -> row_start[N_ENT+1]. Single block.
__global__ __launch_bounds__(1024) void scan_kernel(
    const int* __restrict__ counts, int* __restrict__ row_start)
{
    __shared__ int wsum[16];
    __shared__ int carry_s;
    const int lane = threadIdx.x & 63;
    const int wid  = threadIdx.x >> 6;
    if (threadIdx.x == 0) carry_s = 0;
    __syncthreads();
    for (int base = 0; base < N_ENT; base += 4096) {
        int i0 = base + (int)threadIdx.x * 4;
        int4 v = make_int4(0, 0, 0, 0);
        if (i0 + 3 < N_ENT) v = *(const int4*)(counts + i0);
        else {
            if (i0 + 0 < N_ENT) v.x = counts[i0 + 0];
            if (i0 + 1 < N_ENT) v.y = counts[i0 + 1];
            if (i0 + 2 < N_ENT) v.z = counts[i0 + 2];
            if (i0 + 3 < N_ENT) v.w = counts[i0 + 3];
        }
        int s1 = v.x + v.y, s2 = s1 + v.z, tsum = s2 + v.w;
        int incl = tsum;
#pragma unroll
        for (int off = 1; off < 64; off <<= 1) {
            int t = __shfl_up(incl, off, 64);
            if (lane >= off) incl += t;
        }
        if (lane == 63) wsum[wid] = incl;
        __syncthreads();                              // A
        int wave_off = 0;
#pragma unroll
        for (int w = 0; w < 16; ++w)
            wave_off += (w < wid) ? wsum[w] : 0;
        int carry = carry_s;
        int excl = carry + wave_off + (incl - tsum);
        if (i0 + 3 < N_ENT) {
            *(int4*)(row_start + i0) = make_int4(excl, excl + v.x, excl + s1, excl + s2);
        } else {
            if (i0 + 0 < N_ENT) row_start[i0 + 0] = excl;
            if (i0 + 1 < N_ENT) row_start[i0 + 1] = excl + v.x;
            if (i0 + 2 < N_ENT) row_start[i0 + 2] = excl + s1;
            if (i0 + 3 < N_ENT) row_start[i0 + 3] = excl + s2;
        }
        __syncthreads();                              // B
        if (threadIdx.x == 1023) carry_s = carry + wave_off + incl;
    }
    __syncthreads();
    if (threadIdx.x == 0) row_start[N_ENT] = carry_s;
}

// ---------------------------------------------------------------------------
// Per-edge: compute exp(leaky(score)) directly and scatter RAW exp into CSR.
__global__ __launch_bounds__(256) void scatter_score_kernel(
    const int* __restrict__ eidx, const int* __restrict__ etype,
    const float* __restrict__ ph, const float* __restrict__ pt,
    const float* __restrict__ pr,
    const int* __restrict__ row_start, int* __restrict__ cursor,
    int* __restrict__ csr_col, float* __restrict__ csr_a)
{
    int e = blockIdx.x * 256 + threadIdx.x;
    if (e >= N_EDGE) return;
    int hn = eidx[e];
    int tn = eidx[N_EDGE + e];
    int r  = etype[e];
    float4 a = *(const float4*)(ph + (size_t)hn * 4);
    float4 b = *(const float4*)(pt + (size_t)tn * 4);
    float4 c = *(const float4*)(pr + (size_t)r * 4);
    float s0 = a.x + b.x + c.x;
    float s1 = a.y + b.y + c.y;
    float s2 = a.z + b.z + c.z;
    float s3 = a.w + b.w + c.w;
    s0 = s0 >= 0.f ? s0 : 0.01f * s0;
    s1 = s1 >= 0.f ? s1 : 0.01f * s1;
    s2 = s2 >= 0.f ? s2 : 0.01f * s2;
    s3 = s3 >= 0.f ? s3 : 0.01f * s3;
    float4 ev = make_float4(__expf(s0), __expf(s1), __expf(s2), __expf(s3));
    int pos = row_start[hn] + atomicAdd(&cursor[hn], 1);
    csr_col[pos] = tn;
    *(float4*)(csr_a + (size_t)pos * 4) = ev;
}

// ---------------------------------------------------------------------------
// Row-wise softmax normalize: csr_a[p][h] *= 0.9 / (sum_row csr_a[.][h] + eps)
__global__ __launch_bounds__(256) void normalize_kernel(
    const int* __restrict__ row_start, float* __restrict__ csr_a)
{
    const int wid  = threadIdx.x >> 6;
    const int lane = threadIdx.x & 63;
    const int n = blockIdx.x * 4 + wid;
    if (n >= N_ENT) return;
    const int s   = row_start[n];
    const int end = row_start[n + 1];
    const int nf  = (end - s) * 4;          // floats in this row

    float sum = 0.f;
    for (int f = lane; f < nf; f += 64)
        sum += csr_a[(size_t)s * 4 + f];
#pragma unroll
    for (int off = 4; off < 64; off <<= 1)
        sum += __shfl_xor(sum, off, 64);
    float scale = 0.9f / (sum + 1e-16f);
    for (int f = lane; f < nf; f += 64)
        csr_a[(size_t)s * 4 + f] *= scale;
}

// ---------------------------------------------------------------------------
// SpMM step. Wave per entity; lane handles float4, h = lane/16.
template <bool FIRST>
__global__ __launch_bounds__(256) void spmm_kernel(
    const float* __restrict__ Zin, const float* __restrict__ emb,
    const int* __restrict__ row_start, const int* __restrict__ csr_col,
    const float* __restrict__ csr_a, float* __restrict__ Zout)
{
    const int wave = threadIdx.x >> 6;
    const int lane = threadIdx.x & 63;
    const int n = blockIdx.x * 4 + wave;
    const int h = lane >> 4;

    const float4* e4 = (const float4*)emb;   // [N][16]
    float4 zi = e4[(size_t)n * 16 + (lane & 15)];
    float4 acc0 = make_float4(0.1f * zi.x, 0.1f * zi.y, 0.1f * zi.z, 0.1f * zi.w);
    float4 acc1 = make_float4(0.f, 0.f, 0.f, 0.f);
    float4 acc2 = make_float4(0.f, 0.f, 0.f, 0.f);
    float4 acc3 = make_float4(0.f, 0.f, 0.f, 0.f);

    const int s   = row_start[n];
    const int end = row_start[n + 1];

    auto zrow = [&](int c) -> float4 {
        if (FIRST)
            return *(const float4*)(emb + (size_t)c * 64 + 4 * (lane & 15));
        else
            return *(const float4*)(Zin + (size_t)c * 256 + 4 * lane);
    };
    auto fma4 = [](float4& acc, float a, const float4& z) {
        acc.x = fmaf(a, z.x, acc.x);
        acc.y = fmaf(a, z.y, acc.y);
        acc.z = fmaf(a, z.z, acc.z);
        acc.w = fmaf(a, z.w, acc.w);
    };

    for (int b = s; b < end; b += 16) {
        const int nb = min(16, end - b);
        int   cl = (lane < nb) ? csr_col[b + lane] : 0;
        float al = (lane < nb * 4) ? csr_a[(size_t)b * 4 + lane] : 0.f;

        int j = 0;
        for (; j + 4 <= nb; j += 4) {
            int c0 = __shfl(cl, j + 0, 64);
            int c1 = __shfl(cl, j + 1, 64);
            int c2 = __shfl(cl, j + 2, 64);
            int c3 = __shfl(cl, j + 3, 64);
            float a0 = __shfl(al, (j + 0) * 4 + h, 64);
            float a1 = __shfl(al, (j + 1) * 4 + h, 64);
            float a2 = __shfl(al, (j + 2) * 4 + h, 64);
            float a3 = __shfl(al, (j + 3) * 4 + h, 64);
            float4 za = zrow(c0);
            float4 zb = zrow(c1);
            float4 zc = zrow(c2);
            float4 zd = zrow(c3);
            fma4(acc0, a0, za);
            fma4(acc1, a1, zb);
            fma4(acc2, a2, zc);
            fma4(acc3, a3, zd);
        }
        if (j + 0 < nb) {
            int c = __shfl(cl, j + 0, 64);
            float a = __shfl(al, (j + 0) * 4 + h, 64);
            float4 z = zrow(c);
            fma4(acc0, a, z);
        }
        if (j + 1 < nb) {
            int c = __shfl(cl, j + 1, 64);
            float a = __shfl(al, (j + 1) * 4 + h, 64);
            float4 z = zrow(c);
            fma4(acc1, a, z);
        }
        if (j + 2 < nb) {
            int c = __shfl(cl, j + 2, 64);
            float a = __shfl(al, (j + 2) * 4 + h, 64);
            float4 z = zrow(c);
            fma4(acc2, a, z);
        }
    }
    acc0.x += acc1.x + acc2.x + acc3.x;
    acc0.y += acc1.y + acc2.y + acc3.y;
    acc0.z += acc1.z + acc2.z + acc3.z;
    acc0.w += acc1.w + acc2.w + acc3.w;
    *(float4*)(Zout + (size_t)n * 256 + 4 * lane) = acc0;
}

// ---------------------------------------------------------------------------
// out[100000,64] = Z[100000,256] @ Wo[256,64]. K in 4 chunks of 64 via LDS.
__global__ __launch_bounds__(256) void outproj_kernel(
    const float* __restrict__ Z, const float* __restrict__ Wo,
    float* __restrict__ out)
{
    __shared__ float z_lds[64][68];
    __shared__ float w_lds[64][64];
    const int t = threadIdx.x;
    const int base = blockIdx.x * 64;
    const int er = t & 15;
    const int d0 = (t >> 4) * 4;

    float acc[4][4] = {};
    for (int kc = 0; kc < 4; ++kc) {
        {
            const float4* src = (const float4*)(Wo + (size_t)kc * 64 * 64);
            float4* dst = (float4*)&w_lds[0][0];
#pragma unroll
            for (int i = 0; i < 4; ++i)
                dst[t + 256 * i] = src[t + 256 * i];
        }
        {
#pragma unroll
            for (int i = 0; i < 4; ++i) {
                int f = t + 256 * i;
                int row = f >> 4, c4 = f & 15;
                int gr = min(base + row, N_ENT - 1);
                float4 v = *(const float4*)(Z + (size_t)gr * 256 + kc * 64 + 4 * c4);
                *(float4*)&z_lds[row][4 * c4] = v;
            }
        }
        __syncthreads();

        for (int k4 = 0; k4 < 16; ++k4) {
            float4 z0 = *(const float4*)&z_lds[er +  0][4 * k4];
            float4 z1 = *(const float4*)&z_lds[er + 16][4 * k4];
            float4 z2 = *(const float4*)&z_lds[er + 32][4 * k4];
            float4 z3 = *(const float4*)&z_lds[er + 48][4 * k4];
#pragma unroll
            for (int jj = 0; jj < 4; ++jj) {
                float4 wv = *(const float4*)&w_lds[4 * k4 + jj][d0];
                float zj0 = ((const float*)&z0)[jj];
                float zj1 = ((const float*)&z1)[jj];
                float zj2 = ((const float*)&z2)[jj];
                float zj3 = ((const float*)&z3)[jj];
                acc[0][0] = fmaf(zj0, wv.x, acc[0][0]);
                acc[0][1] = fmaf(zj0, wv.y, acc[0][1]);
                acc[0][2] = fmaf(zj0, wv.z, acc[0][2]);
                acc[0][3] = fmaf(zj0, wv.w, acc[0][3]);
                acc[1][0] = fmaf(zj1, wv.x, acc[1][0]);
                acc[1][1] = fmaf(zj1, wv.y, acc[1][1]);
                acc[1][2] = fmaf(zj1, wv.z, acc[1][2]);
                acc[1][3] = fmaf(zj1, wv.w, acc[1][3]);
                acc[2][0] = fmaf(zj2, wv.x, acc[2][0]);
                acc[2][1] = fmaf(zj2, wv.y, acc[2][1]);
                acc[2][2] = fmaf(zj2, wv.z, acc[2][2]);
                acc[2][3] = fmaf(zj2, wv.w, acc[2][3]);
                acc[3][0] = fmaf(zj3, wv.x, acc[3][0]);
                acc[3][1] = fmaf(zj3, wv.y, acc[3][1]);
                acc[3][2] = fmaf(zj3, wv.z, acc[3][2]);
                acc[3][3] = fmaf(zj3, wv.w, acc[3][3]);
            }
        }
        __syncthreads();
    }

#pragma unroll
    for (int i = 0; i < 4; ++i) {
        int row = base + er + 16 * i;
        if (row < N_ENT) {
            *(float4*)(out + (size_t)row * 64 + d0) =
                make_float4(acc[i][0], acc[i][1], acc[i][2], acc[i][3]);
        }
    }
}

// ---------------------------------------------------------------------------
extern "C" void kernel_launch(void* const* d_in, const int* in_sizes, int n_in,
                              void* d_out, int out_size, void* d_ws, size_t ws_size,
                              hipStream_t stream)
{
    const float* entity = (const float*)d_in[0];
    const float* rel    = (const float*)d_in[1];
    const float* W_h    = (const float*)d_in[2];
    const float* W_t    = (const float*)d_in[3];
    const float* W_r    = (const float*)d_in[4];
    const float* att_h  = (const float*)d_in[5];
    const float* att_t  = (const float*)d_in[6];
    const float* att_r  = (const float*)d_in[7];
    const float* W_o    = (const float*)d_in[8];
    const int*   eidx   = (const int*)d_in[9];   // [2,E]
    const int*   etype  = (const int*)d_in[10];  // [E]
    float* out = (float*)d_out;

    char* ws = (char*)d_ws;
    size_t off = 0;
    auto alloc = [&](size_t bytes) -> void* {
        void* p = ws + off;
        off += (bytes + 255) & ~(size_t)255;
        return p;
    };
    float* p_h      = (float*)alloc((size_t)N_ENT * 4 * 4);
    float* p_t      = (float*)alloc((size_t)N_ENT * 4 * 4);
    float* p_r      = (float*)alloc((size_t)N_REL * 4 * 4);
    int*   counts   = (int*)alloc((size_t)N_ENT * 4);
    int*   row_start= (int*)alloc(((size_t)N_ENT + 1) * 4);
    int*   cursor   = (int*)alloc((size_t)N_ENT * 4);
    int*   csr_col  = (int*)alloc((size_t)N_EDGE * 4);
    float* csr_a    = (float*)alloc((size_t)N_EDGE * 4 * 4);
    float* Za       = (float*)alloc((size_t)N_ENT * 256 * 4);
    float* Zb       = (float*)alloc((size_t)N_ENT * 256 * 4);

    hipMemsetAsync(counts, 0, (size_t)N_ENT * 4, stream);
    hipMemsetAsync(cursor, 0, (size_t)N_ENT * 4, stream);

    // fused h/t projections (shared embed staging) + relation projection
    proj_gemm_kernel<2><<<(N_ENT + 63) / 64, 256, 0, stream>>>(
        entity, W_h, att_h, p_h, W_t, att_t, p_t, N_ENT);
    proj_gemm_kernel<1><<<(N_REL + 63) / 64, 256, 0, stream>>>(
        rel, W_r, att_r, p_r, nullptr, nullptr, nullptr, N_REL);

    hist_kernel<<<(N_EDGE + 255) / 256, 256, 0, stream>>>(eidx, counts);
    scan_kernel<<<1, 1024, 0, stream>>>(counts, row_start);
    scatter_score_kernel<<<(N_EDGE + 255) / 256, 256, 0, stream>>>(
        eidx, etype, p_h, p_t, p_r, row_start, cursor, csr_col, csr_a);
    normalize_kernel<<<(N_ENT + 3) / 4, 256, 0, stream>>>(row_start, csr_a);

    // power iteration: Z1..Z5 (first step reads emb broadcast directly)
    spmm_kernel<true ><<<N_ENT / 4, 256, 0, stream>>>(nullptr, entity, row_start, csr_col, csr_a, Zb);
    spmm_kernel<false><<<N_ENT / 4, 256, 0, stream>>>(Zb, entity, row_start, csr_col, csr_a, Za);
    spmm_kernel<false><<<N_ENT / 4, 256, 0, stream>>>(Za, entity, row_start, csr_col, csr_a, Zb);
    spmm_kernel<false><<<N_ENT / 4, 256, 0, stream>>>(Zb, entity, row_start, csr_col, csr_a, Za);
    spmm_kernel<false><<<N_ENT / 4, 256, 0, stream>>>(Za, entity, row_start, csr_col, csr_a, Zb);

    outproj_kernel<<<(N_ENT + 63) / 64, 256, 0, stream>>>(Zb, W_o, out);
}

// Round 6
// 535.501 us; speedup vs baseline: 2.6177x; 1.2937x over previous
//
#include <hip/hip_runtime.h>
#include <hip/hip_fp16.h>
#include <math.h>

#define N_ENT 100000
#define N_EDGE 500000
#define N_REL 200
// DIM=64, HEADS=4, HD=256

__device__ __forceinline__ float fast_tanh(float x) {
    float xc = fminf(x, 15.f);
    float e = __expf(2.f * xc);
    return (e - 1.f) / (e + 1.f);
}

__device__ __forceinline__ uint2 pack_half4(const float4 v) {
    __half2 lo = __floats2half2_rn(v.x, v.y);
    __half2 hi = __floats2half2_rn(v.z, v.w);
    uint2 r;
    r.x = *reinterpret_cast<const unsigned int*>(&lo);
    r.y = *reinterpret_cast<const unsigned int*>(&hi);
    return r;
}

__device__ __forceinline__ float4 unpack_half4(uint2 u) {
    __half2 lo = *reinterpret_cast<const __half2*>(&u.x);
    __half2 hi = *reinterpret_cast<const __half2*>(&u.y);
    float2 a = __half22float2(lo);
    float2 b = __half22float2(hi);
    return make_float4(a.x, a.y, b.x, b.y);
}

// ---------------------------------------------------------------------------
// Fused attention projections. For each mat m: p_m[n,h] =
// sum_d tanh((emb[n,:]@W_m)[h*64+d]) * att_m[h,d].
// Block = 64 entities. Per head: stage W chunks for BOTH mats, one k-loop
// shares the e_lds reads. Per-head results kept in registers; single
// reduction phase at the end.
template <int NMAT>
__global__ __launch_bounds__(256) void proj_gemm_kernel(
    const float* __restrict__ emb,     // [nrows,64]
    const float* __restrict__ W0,      // [64,256]
    const float* __restrict__ att0,    // [4,64]
    float* __restrict__ p0,            // [nrows,4]
    const float* __restrict__ W1,
    const float* __restrict__ att1,
    float* __restrict__ p1,
    int nrows)
{
    __shared__ float e_lds[64][68];
    __shared__ float w0_lds[64][64];
    __shared__ float w1_lds[(NMAT == 2) ? 64 : 1][(NMAT == 2) ? 64 : 1];
    __shared__ float red[4][4][64];    // [wave][head][er+16*i]

    const int t    = threadIdx.x;
    const int wv   = t >> 6;
    const int lane = t & 63;
    const int er   = t & 15;
    const int d0   = (t >> 4) * 4;
    const int base = blockIdx.x * 64;

    // stage embed tile (coalesced float4), clamp OOB rows
#pragma unroll
    for (int i = 0; i < 4; ++i) {
        int f = t + 256 * i;              // 0..1023
        int row = f >> 4, c4 = f & 15;
        int gr = min(base + row, nrows - 1);
        float4 v = *(const float4*)(emb + (size_t)gr * 64 + 4 * c4);
        *(float4*)&e_lds[row][4 * c4] = v;
    }

    float p0s[4][4];   // [head][i]
    float p1s[4][4];

    for (int head = 0; head < 4; ++head) {
        // stage W chunks: w_lds[k][c] = W[k][head*64+c]
        {
            int k0 = t >> 4, c4 = t & 15;
#pragma unroll
            for (int kk = 0; kk < 4; ++kk) {
                int k = k0 + 16 * kk;
                *(float4*)&w0_lds[k][4 * c4] =
                    *(const float4*)(W0 + (size_t)k * 256 + head * 64 + 4 * c4);
                if (NMAT == 2)
                    *(float4*)&w1_lds[k][4 * c4] =
                        *(const float4*)(W1 + (size_t)k * 256 + head * 64 + 4 * c4);
            }
        }
        __syncthreads();

        float acc0[4][4] = {};
        float acc1[4][4] = {};
        for (int k4 = 0; k4 < 16; ++k4) {
            float4 z0 = *(const float4*)&e_lds[er +  0][4 * k4];
            float4 z1 = *(const float4*)&e_lds[er + 16][4 * k4];
            float4 z2 = *(const float4*)&e_lds[er + 32][4 * k4];
            float4 z3 = *(const float4*)&e_lds[er + 48][4 * k4];
            const float zr[4][4] = {
                {z0.x, z0.y, z0.z, z0.w},
                {z1.x, z1.y, z1.z, z1.w},
                {z2.x, z2.y, z2.z, z2.w},
                {z3.x, z3.y, z3.z, z3.w}};
#pragma unroll
            for (int jj = 0; jj < 4; ++jj) {
                float4 w0v = *(const float4*)&w0_lds[4 * k4 + jj][d0];
#pragma unroll
                for (int i = 0; i < 4; ++i) {
                    float zj = zr[i][jj];
                    acc0[i][0] = fmaf(zj, w0v.x, acc0[i][0]);
                    acc0[i][1] = fmaf(zj, w0v.y, acc0[i][1]);
                    acc0[i][2] = fmaf(zj, w0v.z, acc0[i][2]);
                    acc0[i][3] = fmaf(zj, w0v.w, acc0[i][3]);
                }
                if (NMAT == 2) {
                    float4 w1v = *(const float4*)&w1_lds[4 * k4 + jj][d0];
#pragma unroll
                    for (int i = 0; i < 4; ++i) {
                        float zj = zr[i][jj];
                        acc1[i][0] = fmaf(zj, w1v.x, acc1[i][0]);
                        acc1[i][1] = fmaf(zj, w1v.y, acc1[i][1]);
                        acc1[i][2] = fmaf(zj, w1v.z, acc1[i][2]);
                        acc1[i][3] = fmaf(zj, w1v.w, acc1[i][3]);
                    }
                }
            }
        }

        // tanh + att weighting + in-wave reduce (cols d0.., lanes er+16i)
        float4 av0 = *(const float4*)(att0 + head * 64 + d0);
#pragma unroll
        for (int i = 0; i < 4; ++i) {
            float v = fast_tanh(acc0[i][0]) * av0.x
                    + fast_tanh(acc0[i][1]) * av0.y
                    + fast_tanh(acc0[i][2]) * av0.z
                    + fast_tanh(acc0[i][3]) * av0.w;
            v += __shfl_xor(v, 16, 64);
            v += __shfl_xor(v, 32, 64);
            p0s[head][i] = v;
        }
        if (NMAT == 2) {
            float4 av1 = *(const float4*)(att1 + head * 64 + d0);
#pragma unroll
            for (int i = 0; i < 4; ++i) {
                float v = fast_tanh(acc1[i][0]) * av1.x
                        + fast_tanh(acc1[i][1]) * av1.y
                        + fast_tanh(acc1[i][2]) * av1.z
                        + fast_tanh(acc1[i][3]) * av1.w;
                v += __shfl_xor(v, 16, 64);
                v += __shfl_xor(v, 32, 64);
                p1s[head][i] = v;
            }
        }
        __syncthreads();   // before next head overwrites w_lds
    }

    // ---- end-phase reduction: mat0 ----
    if (lane < 16) {
#pragma unroll
        for (int h = 0; h < 4; ++h)
#pragma unroll
            for (int i = 0; i < 4; ++i)
                red[wv][h][lane + 16 * i] = p0s[h][i];
    }
    __syncthreads();
    if (t < 64) {
        int row = base + t;
        if (row < nrows) {
            float4 pv;
            pv.x = red[0][0][t] + red[1][0][t] + red[2][0][t] + red[3][0][t];
            pv.y = red[0][1][t] + red[1][1][t] + red[2][1][t] + red[3][1][t];
            pv.z = red[0][2][t] + red[1][2][t] + red[2][2][t] + red[3][2][t];
            pv.w = red[0][3][t] + red[1][3][t] + red[2][3][t] + red[3][3][t];
            *(float4*)(p0 + (size_t)row * 4) = pv;
        }
    }
    if (NMAT == 2) {
        __syncthreads();
        if (lane < 16) {
#pragma unroll
            for (int h = 0; h < 4; ++h)
#pragma unroll
                for (int i = 0; i < 4; ++i)
                    red[wv][h][lane + 16 * i] = p1s[h][i];
        }
        __syncthreads();
        if (t < 64) {
            int row = base + t;
            if (row < nrows) {
                float4 pv;
                pv.x = red[0][0][t] + red[1][0][t] + red[2][0][t] + red[3][0][t];
                pv.y = red[0][1][t] + red[1][1][t] + red[2][1][t] + red[3][1][t];
                pv.z = red[0][2][t] + red[1][2][t] + red[2][2][t] + red[3][2][t];
                pv.w = red[0][3][t] + red[1][3][t] + red[2][3][t] + red[3][3][t];
                *(float4*)(p1 + (size_t)row * 4) = pv;
            }
        }
    }
}

// ---------------------------------------------------------------------------
// Degree histogram: 1 atomic per edge.
__global__ __launch_bounds__(256) void hist_kernel(
    const int* __restrict__ eidx, int* __restrict__ counts)
{
    int e = blockIdx.x * 256 + threadIdx.x;
    if (e >= N_EDGE) return;
    atomicAdd(&counts[eidx[e]], 1);
}

// ---------------------------------------------------------------------------
// Exclusive scan of counts[N_ENT] -> row_start[N_ENT+1]. Single block.
__global__ __launch_bounds__(1024) void scan_kernel(
    const int* __restrict__ counts, int* __restrict__ row_start)
{
    __shared__ int wsum[16];
    __shared__ int carry_s;
    const int lane = threadIdx.x & 63;
    const int wid  = threadIdx.x >> 6;
    if (threadIdx.x == 0) carry_s = 0;
    __syncthreads();
    for (int base = 0; base < N_ENT; base += 4096) {
        int i0 = base + (int)threadIdx.x * 4;
        int4 v = make_int4(0, 0, 0, 0);
        if (i0 + 3 < N_ENT) v = *(const int4*)(counts + i0);
        else {
            if (i0 + 0 < N_ENT) v.x = counts[i0 + 0];
            if (i0 + 1 < N_ENT) v.y = counts[i0 + 1];
            if (i0 + 2 < N_ENT) v.z = counts[i0 + 2];
            if (i0 + 3 < N_ENT) v.w = counts[i0 + 3];
        }
        int s1 = v.x + v.y, s2 = s1 + v.z, tsum = s2 + v.w;
        int incl = tsum;
#pragma unroll
        for (int off = 1; off < 64; off <<= 1) {
            int t = __shfl_up(incl, off, 64);
            if (lane >= off) incl += t;
        }
        if (lane == 63) wsum[wid] = incl;
        __syncthreads();                              // A
        int wave_off = 0;
#pragma unroll
        for (int w = 0; w < 16; ++w)
            wave_off += (w < wid) ? wsum[w] : 0;
        int carry = carry_s;
        int excl = carry + wave_off + (incl - tsum);
        if (i0 + 3 < N_ENT) {
            *(int4*)(row_start + i0) = make_int4(excl, excl + v.x, excl + s1, excl + s2);
        } else {
            if (i0 + 0 < N_ENT) row_start[i0 + 0] = excl;
            if (i0 + 1 < N_ENT) row_start[i0 + 1] = excl + v.x;
            if (i0 + 2 < N_ENT) row_start[i0 + 2] = excl + s1;
            if (i0 + 3 < N_ENT) row_start[i0 + 3] = excl + s2;
        }
        __syncthreads();                              // B
        if (threadIdx.x == 1023) carry_s = carry + wave_off + incl;
    }
    __syncthreads();
    if (threadIdx.x == 0) row_start[N_ENT] = carry_s;
}

// ---------------------------------------------------------------------------
// Per-edge: compute exp(leaky(score)) directly and scatter RAW exp into CSR.
__global__ __launch_bounds__(256) void scatter_score_kernel(
    const int* __restrict__ eidx, const int* __restrict__ etype,
    const float* __restrict__ ph, const float* __restrict__ pt,
    const float* __restrict__ pr,
    const int* __restrict__ row_start, int* __restrict__ cursor,
    int* __restrict__ csr_col, float* __restrict__ csr_a)
{
    int e = blockIdx.x * 256 + threadIdx.x;
    if (e >= N_EDGE) return;
    int hn = eidx[e];
    int tn = eidx[N_EDGE + e];
    int r  = etype[e];
    float4 a = *(const float4*)(ph + (size_t)hn * 4);
    float4 b = *(const float4*)(pt + (size_t)tn * 4);
    float4 c = *(const float4*)(pr + (size_t)r * 4);
    float s0 = a.x + b.x + c.x;
    float s1 = a.y + b.y + c.y;
    float s2 = a.z + b.z + c.z;
    float s3 = a.w + b.w + c.w;
    s0 = s0 >= 0.f ? s0 : 0.01f * s0;
    s1 = s1 >= 0.f ? s1 : 0.01f * s1;
    s2 = s2 >= 0.f ? s2 : 0.01f * s2;
    s3 = s3 >= 0.f ? s3 : 0.01f * s3;
    float4 ev = make_float4(__expf(s0), __expf(s1), __expf(s2), __expf(s3));
    int pos = row_start[hn] + atomicAdd(&cursor[hn], 1);
    csr_col[pos] = tn;
    *(float4*)(csr_a + (size_t)pos * 4) = ev;
}

// ---------------------------------------------------------------------------
// Row-wise softmax normalize: csr_a[p][h] *= 0.9 / (sum_row csr_a[.][h] + eps)
__global__ __launch_bounds__(256) void normalize_kernel(
    const int* __restrict__ row_start, float* __restrict__ csr_a)
{
    const int wid  = threadIdx.x >> 6;
    const int lane = threadIdx.x & 63;
    const int n = blockIdx.x * 4 + wid;
    if (n >= N_ENT) return;
    const int s   = row_start[n];
    const int end = row_start[n + 1];
    const int nf  = (end - s) * 4;          // floats in this row

    float sum = 0.f;
    for (int f = lane; f < nf; f += 64)
        sum += csr_a[(size_t)s * 4 + f];
#pragma unroll
    for (int off = 4; off < 64; off <<= 1)
        sum += __shfl_xor(sum, off, 64);
    float scale = 0.9f / (sum + 1e-16f);
    for (int f = lane; f < nf; f += 64)
        csr_a[(size_t)s * 4 + f] *= scale;
}

// ---------------------------------------------------------------------------
// SpMM step. Wave per entity; lane handles cols 4*lane..+3, h = lane/16.
// IN_HALF: gather Z rows as fp16 (8B/lane); else broadcast-read emb fp32.
// OUT_HALF: write fp16 row (8B/lane) else fp32.
template <bool IN_HALF, bool OUT_HALF>
__global__ __launch_bounds__(256) void spmm_kernel(
    const void* __restrict__ Zin_v, const float* __restrict__ emb,
    const int* __restrict__ row_start, const int* __restrict__ csr_col,
    const float* __restrict__ csr_a, void* __restrict__ Zout_v)
{
    const int wave = threadIdx.x >> 6;
    const int lane = threadIdx.x & 63;
    const int n = blockIdx.x * 4 + wave;
    const int h = lane >> 4;
    const __half* Zin_h = (const __half*)Zin_v;

    const float4* e4 = (const float4*)emb;   // [N][16]
    float4 zi = e4[(size_t)n * 16 + (lane & 15)];
    float4 acc0 = make_float4(0.1f * zi.x, 0.1f * zi.y, 0.1f * zi.z, 0.1f * zi.w);
    float4 acc1 = make_float4(0.f, 0.f, 0.f, 0.f);
    float4 acc2 = make_float4(0.f, 0.f, 0.f, 0.f);
    float4 acc3 = make_float4(0.f, 0.f, 0.f, 0.f);

    const int s   = row_start[n];
    const int end = row_start[n + 1];

    auto zrow = [&](int c) -> float4 {
        if (IN_HALF) {
            uint2 u = *(const uint2*)(Zin_h + (size_t)c * 256 + 4 * lane);
            return unpack_half4(u);
        } else {
            return *(const float4*)(emb + (size_t)c * 64 + 4 * (lane & 15));
        }
    };
    auto fma4 = [](float4& acc, float a, const float4& z) {
        acc.x = fmaf(a, z.x, acc.x);
        acc.y = fmaf(a, z.y, acc.y);
        acc.z = fmaf(a, z.z, acc.z);
        acc.w = fmaf(a, z.w, acc.w);
    };

    for (int b = s; b < end; b += 16) {
        const int nb = min(16, end - b);
        int   cl = (lane < nb) ? csr_col[b + lane] : 0;
        float al = (lane < nb * 4) ? csr_a[(size_t)b * 4 + lane] : 0.f;

        int j = 0;
        for (; j + 4 <= nb; j += 4) {
            int c0 = __shfl(cl, j + 0, 64);
            int c1 = __shfl(cl, j + 1, 64);
            int c2 = __shfl(cl, j + 2, 64);
            int c3 = __shfl(cl, j + 3, 64);
            float a0 = __shfl(al, (j + 0) * 4 + h, 64);
            float a1 = __shfl(al, (j + 1) * 4 + h, 64);
            float a2 = __shfl(al, (j + 2) * 4 + h, 64);
            float a3 = __shfl(al, (j + 3) * 4 + h, 64);
            float4 za = zrow(c0);
            float4 zb = zrow(c1);
            float4 zc = zrow(c2);
            float4 zd = zrow(c3);
            fma4(acc0, a0, za);
            fma4(acc1, a1, zb);
            fma4(acc2, a2, zc);
            fma4(acc3, a3, zd);
        }
        if (j + 0 < nb) {
            int c = __shfl(cl, j + 0, 64);
            float a = __shfl(al, (j + 0) * 4 + h, 64);
            float4 z = zrow(c);
            fma4(acc0, a, z);
        }
        if (j + 1 < nb) {
            int c = __shfl(cl, j + 1, 64);
            float a = __shfl(al, (j + 1) * 4 + h, 64);
            float4 z = zrow(c);
            fma4(acc1, a, z);
        }
        if (j + 2 < nb) {
            int c = __shfl(cl, j + 2, 64);
            float a = __shfl(al, (j + 2) * 4 + h, 64);
            float4 z = zrow(c);
            fma4(acc2, a, z);
        }
    }
    acc0.x += acc1.x + acc2.x + acc3.x;
    acc0.y += acc1.y + acc2.y + acc3.y;
    acc0.z += acc1.z + acc2.z + acc3.z;
    acc0.w += acc1.w + acc2.w + acc3.w;

    if (OUT_HALF)
        *(uint2*)((__half*)Zout_v + (size_t)n * 256 + 4 * lane) = pack_half4(acc0);
    else
        *(float4*)((float*)Zout_v + (size_t)n * 256 + 4 * lane) = acc0;
}

// ---------------------------------------------------------------------------
// out[100000,64] = Z[100000,256] @ Wo[256,64]. K in 4 chunks of 64 via LDS.
__global__ __launch_bounds__(256) void outproj_kernel(
    const float* __restrict__ Z, const float* __restrict__ Wo,
    float* __restrict__ out)
{
    __shared__ float z_lds[64][68];
    __shared__ float w_lds[64][64];
    const int t = threadIdx.x;
    const int base = blockIdx.x * 64;
    const int er = t & 15;
    const int d0 = (t >> 4) * 4;

    float acc[4][4] = {};
    for (int kc = 0; kc < 4; ++kc) {
        {
            const float4* src = (const float4*)(Wo + (size_t)kc * 64 * 64);
            float4* dst = (float4*)&w_lds[0][0];
#pragma unroll
            for (int i = 0; i < 4; ++i)
                dst[t + 256 * i] = src[t + 256 * i];
        }
        {
#pragma unroll
            for (int i = 0; i < 4; ++i) {
                int f = t + 256 * i;
                int row = f >> 4, c4 = f & 15;
                int gr = min(base + row, N_ENT - 1);
                float4 v = *(const float4*)(Z + (size_t)gr * 256 + kc * 64 + 4 * c4);
                *(float4*)&z_lds[row][4 * c4] = v;
            }
        }
        __syncthreads();

        for (int k4 = 0; k4 < 16; ++k4) {
            float4 z0 = *(const float4*)&z_lds[er +  0][4 * k4];
            float4 z1 = *(const float4*)&z_lds[er + 16][4 * k4];
            float4 z2 = *(const float4*)&z_lds[er + 32][4 * k4];
            float4 z3 = *(const float4*)&z_lds[er + 48][4 * k4];
#pragma unroll
            for (int jj = 0; jj < 4; ++jj) {
                float4 wv = *(const float4*)&w_lds[4 * k4 + jj][d0];
                float zj0 = ((const float*)&z0)[jj];
                float zj1 = ((const float*)&z1)[jj];
                float zj2 = ((const float*)&z2)[jj];
                float zj3 = ((const float*)&z3)[jj];
                acc[0][0] = fmaf(zj0, wv.x, acc[0][0]);
                acc[0][1] = fmaf(zj0, wv.y, acc[0][1]);
                acc[0][2] = fmaf(zj0, wv.z, acc[0][2]);
                acc[0][3] = fmaf(zj0, wv.w, acc[0][3]);
                acc[1][0] = fmaf(zj1, wv.x, acc[1][0]);
                acc[1][1] = fmaf(zj1, wv.y, acc[1][1]);
                acc[1][2] = fmaf(zj1, wv.z, acc[1][2]);
                acc[1][3] = fmaf(zj1, wv.w, acc[1][3]);
                acc[2][0] = fmaf(zj2, wv.x, acc[2][0]);
                acc[2][1] = fmaf(zj2, wv.y, acc[2][1]);
                acc[2][2] = fmaf(zj2, wv.z, acc[2][2]);
                acc[2][3] = fmaf(zj2, wv.w, acc[2][3]);
                acc[3][0] = fmaf(zj3, wv.x, acc[3][0]);
                acc[3][1] = fmaf(zj3, wv.y, acc[3][1]);
                acc[3][2] = fmaf(zj3, wv.z, acc[3][2]);
                acc[3][3] = fmaf(zj3, wv.w, acc[3][3]);
            }
        }
        __syncthreads();
    }

#pragma unroll
    for (int i = 0; i < 4; ++i) {
        int row = base + er + 16 * i;
        if (row < N_ENT) {
            *(float4*)(out + (size_t)row * 64 + d0) =
                make_float4(acc[i][0], acc[i][1], acc[i][2], acc[i][3]);
        }
    }
}

// ---------------------------------------------------------------------------
extern "C" void kernel_launch(void* const* d_in, const int* in_sizes, int n_in,
                              void* d_out, int out_size, void* d_ws, size_t ws_size,
                              hipStream_t stream)
{
    const float* entity = (const float*)d_in[0];
    const float* rel    = (const float*)d_in[1];
    const float* W_h    = (const float*)d_in[2];
    const float* W_t    = (const float*)d_in[3];
    const float* W_r    = (const float*)d_in[4];
    const float* att_h  = (const float*)d_in[5];
    const float* att_t  = (const float*)d_in[6];
    const float* att_r  = (const float*)d_in[7];
    const float* W_o    = (const float*)d_in[8];
    const int*   eidx   = (const int*)d_in[9];   // [2,E]
    const int*   etype  = (const int*)d_in[10];  // [E]
    float* out = (float*)d_out;

    char* ws = (char*)d_ws;
    size_t off = 0;
    auto alloc = [&](size_t bytes) -> void* {
        void* p = ws + off;
        off += (bytes + 255) & ~(size_t)255;
        return p;
    };
    float* p_h      = (float*)alloc((size_t)N_ENT * 4 * 4);
    float* p_t      = (float*)alloc((size_t)N_ENT * 4 * 4);
    float* p_r      = (float*)alloc((size_t)N_REL * 4 * 4);
    int*   counts   = (int*)alloc((size_t)N_ENT * 4);
    int*   row_start= (int*)alloc(((size_t)N_ENT + 1) * 4);
    int*   cursor   = (int*)alloc((size_t)N_ENT * 4);
    int*   csr_col  = (int*)alloc((size_t)N_EDGE * 4);
    float* csr_a    = (float*)alloc((size_t)N_EDGE * 4 * 4);
    __half* Zh_a    = (__half*)alloc((size_t)N_ENT * 256 * 2);
    __half* Zh_b    = (__half*)alloc((size_t)N_ENT * 256 * 2);
    float* Zf       = (float*)alloc((size_t)N_ENT * 256 * 4);

    hipMemsetAsync(counts, 0, (size_t)N_ENT * 4, stream);
    hipMemsetAsync(cursor, 0, (size_t)N_ENT * 4, stream);

    // fused h/t projections (shared embed staging) + relation projection
    proj_gemm_kernel<2><<<(N_ENT + 63) / 64, 256, 0, stream>>>(
        entity, W_h, att_h, p_h, W_t, att_t, p_t, N_ENT);
    proj_gemm_kernel<1><<<(N_REL + 63) / 64, 256, 0, stream>>>(
        rel, W_r, att_r, p_r, nullptr, nullptr, nullptr, N_REL);

    hist_kernel<<<(N_EDGE + 255) / 256, 256, 0, stream>>>(eidx, counts);
    scan_kernel<<<1, 1024, 0, stream>>>(counts, row_start);
    scatter_score_kernel<<<(N_EDGE + 255) / 256, 256, 0, stream>>>(
        eidx, etype, p_h, p_t, p_r, row_start, cursor, csr_col, csr_a);
    normalize_kernel<<<(N_ENT + 3) / 4, 256, 0, stream>>>(row_start, csr_a);

    // power iteration: Z1..Z5. Intermediates fp16, final fp32.
    spmm_kernel<false, true ><<<N_ENT / 4, 256, 0, stream>>>(nullptr, entity, row_start, csr_col, csr_a, Zh_b);
    spmm_kernel<true,  true ><<<N_ENT / 4, 256, 0, stream>>>(Zh_b, entity, row_start, csr_col, csr_a, Zh_a);
    spmm_kernel<true,  true ><<<N_ENT / 4, 256, 0, stream>>>(Zh_a, entity, row_start, csr_col, csr_a, Zh_b);
    spmm_kernel<true,  true ><<<N_ENT / 4, 256, 0, stream>>>(Zh_b, entity, row_start, csr_col, csr_a, Zh_a);
    spmm_kernel<true,  false><<<N_ENT / 4, 256, 0, stream>>>(Zh_a, entity, row_start, csr_col, csr_a, Zf);

    outproj_kernel<<<(N_ENT + 63) / 64, 256, 0, stream>>>(Zf, W_o, out);
}

// Round 7
// 497.776 us; speedup vs baseline: 2.8161x; 1.0758x over previous
//
#include <hip/hip_runtime.h>
#include <hip/hip_fp16.h>
#include <math.h>

#define N_ENT 100000
#define N_EDGE 500000
#define N_REL 200
// DIM=64, HEADS=4, HD=256

typedef short bf16x8 __attribute__((ext_vector_type(8)));
typedef float f32x4 __attribute__((ext_vector_type(4)));

__device__ __forceinline__ float fast_tanh(float x) {
    float xc = fminf(x, 15.f);
    float e = __expf(2.f * xc);
    return (e - 1.f) / (e + 1.f);
}

__device__ __forceinline__ unsigned short f2bf(float f) {
    unsigned u = __float_as_uint(f);
    unsigned r = u + 0x7FFF + ((u >> 16) & 1);   // round-to-nearest-even
    return (unsigned short)(r >> 16);
}

__device__ __forceinline__ uint2 pack_half4(const float4 v) {
    __half2 lo = __floats2half2_rn(v.x, v.y);
    __half2 hi = __floats2half2_rn(v.z, v.w);
    uint2 r;
    r.x = *reinterpret_cast<const unsigned int*>(&lo);
    r.y = *reinterpret_cast<const unsigned int*>(&hi);
    return r;
}

__device__ __forceinline__ float4 unpack_half4(uint2 u) {
    __half2 lo = *reinterpret_cast<const __half2*>(&u.x);
    __half2 hi = *reinterpret_cast<const __half2*>(&u.y);
    float2 a = __half22float2(lo);
    float2 b = __half22float2(hi);
    return make_float4(a.x, a.y, b.x, b.y);
}

// ---------------------------------------------------------------------------
// Convert entity_embed fp32 -> bf16 (RNE), vectorized 4/thread.
__global__ __launch_bounds__(256) void cvt_emb_kernel(
    const float* __restrict__ in, unsigned short* __restrict__ out, int nquads)
{
    for (int i = blockIdx.x * 256 + threadIdx.x; i < nquads; i += gridDim.x * 256) {
        float4 v = ((const float4*)in)[i];
        ushort4 o;
        o.x = f2bf(v.x); o.y = f2bf(v.y); o.z = f2bf(v.z); o.w = f2bf(v.w);
        ((ushort4*)out)[i] = o;
    }
}

// ---------------------------------------------------------------------------
// Build wT[(mat*256+col)*64 + k] = bf16(W_mat[k*256+col]). 32768 elems.
__global__ __launch_bounds__(256) void cvt_wT_kernel(
    const float* __restrict__ W0, const float* __restrict__ W1,
    unsigned short* __restrict__ wT)
{
    int idx = blockIdx.x * 256 + threadIdx.x;     // 0..32767
    if (idx >= 2 * 256 * 64) return;
    int mat = idx >> 14;
    int rem = idx & 16383;
    int col = rem >> 6;
    int k   = rem & 63;
    const float* W = (mat == 0) ? W0 : W1;
    wT[idx] = f2bf(W[k * 256 + col]);
}

// ---------------------------------------------------------------------------
// MFMA attention projections for h and t (shared A = entity embed).
// Wave w of block b owns 16 entity rows. A-frags in regs; B streamed from
// L2-hot wT. C layout (HW-verified): col=lane&15, row=(lane>>4)*4+reg.
// A/B k-mapping self-consistent (same bijection both operands).
__global__ __launch_bounds__(256) void proj_mfma_kernel(
    const unsigned short* __restrict__ emb_bf,   // [N][64] bf16
    const unsigned short* __restrict__ wT,       // [2*256][64] bf16
    const float* __restrict__ att0, const float* __restrict__ att1,
    float* __restrict__ p0, float* __restrict__ p1, int nrows)
{
    const int wv   = threadIdx.x >> 6;
    const int lane = threadIdx.x & 63;
    const int r4   = lane >> 4;        // k-group / C-row-quad selector
    const int cl   = lane & 15;        // A-row / B-col / C-col selector
    const int rowbase = blockIdx.x * 64 + wv * 16;

    int ra = min(rowbase + cl, nrows - 1);
    bf16x8 a0 = *(const bf16x8*)(emb_bf + (size_t)ra * 64 + 8 * r4);
    bf16x8 a1 = *(const bf16x8*)(emb_bf + (size_t)ra * 64 + 8 * r4 + 32);

#pragma unroll
    for (int mat = 0; mat < 2; ++mat) {
        const float* att = (mat == 0) ? att0 : att1;
        float* p         = (mat == 0) ? p0 : p1;
        float pacc[4][4];   // [head][j]
#pragma unroll
        for (int head = 0; head < 4; ++head) {
            float ph_[4] = {0.f, 0.f, 0.f, 0.f};
#pragma unroll
            for (int sub = 0; sub < 4; ++sub) {
                int col = head * 64 + sub * 16 + cl;
                const unsigned short* wp =
                    wT + ((size_t)(mat * 256 + col)) * 64 + 8 * r4;
                bf16x8 b0 = *(const bf16x8*)(wp);
                bf16x8 b1 = *(const bf16x8*)(wp + 32);
                f32x4 c = {0.f, 0.f, 0.f, 0.f};
                c = __builtin_amdgcn_mfma_f32_16x16x32_bf16(a0, b0, c, 0, 0, 0);
                c = __builtin_amdgcn_mfma_f32_16x16x32_bf16(a1, b1, c, 0, 0, 0);
                float av = att[head * 64 + sub * 16 + cl];
#pragma unroll
                for (int j = 0; j < 4; ++j) {
                    float v = fast_tanh(c[j]) * av;
                    v += __shfl_xor(v, 1, 64);
                    v += __shfl_xor(v, 2, 64);
                    v += __shfl_xor(v, 4, 64);
                    v += __shfl_xor(v, 8, 64);
                    ph_[j] += v;
                }
            }
#pragma unroll
            for (int j = 0; j < 4; ++j) pacc[head][j] = ph_[j];
        }
        if (cl == 0) {
#pragma unroll
            for (int j = 0; j < 4; ++j) {
                int row = rowbase + r4 * 4 + j;
                if (row < nrows) {
                    *(float4*)(p + (size_t)row * 4) = make_float4(
                        pacc[0][j], pacc[1][j], pacc[2][j], pacc[3][j]);
                }
            }
        }
    }
}

// ---------------------------------------------------------------------------
// VALU projection for relations (only 200 rows — not worth MFMA).
__global__ __launch_bounds__(256) void proj_gemm_kernel(
    const float* __restrict__ emb,     // [nrows,64]
    const float* __restrict__ W0,      // [64,256]
    const float* __restrict__ att0,    // [4,64]
    float* __restrict__ p0,            // [nrows,4]
    int nrows)
{
    __shared__ float e_lds[64][68];
    __shared__ float w0_lds[64][64];
    __shared__ float red[4][4][64];    // [wave][head][er+16*i]

    const int t    = threadIdx.x;
    const int wv   = t >> 6;
    const int lane = t & 63;
    const int er   = t & 15;
    const int d0   = (t >> 4) * 4;
    const int base = blockIdx.x * 64;

#pragma unroll
    for (int i = 0; i < 4; ++i) {
        int f = t + 256 * i;
        int row = f >> 4, c4 = f & 15;
        int gr = min(base + row, nrows - 1);
        float4 v = *(const float4*)(emb + (size_t)gr * 64 + 4 * c4);
        *(float4*)&e_lds[row][4 * c4] = v;
    }

    float p0s[4][4];

    for (int head = 0; head < 4; ++head) {
        {
            int k0 = t >> 4, c4 = t & 15;
#pragma unroll
            for (int kk = 0; kk < 4; ++kk) {
                int k = k0 + 16 * kk;
                *(float4*)&w0_lds[k][4 * c4] =
                    *(const float4*)(W0 + (size_t)k * 256 + head * 64 + 4 * c4);
            }
        }
        __syncthreads();

        float acc0[4][4] = {};
        for (int k4 = 0; k4 < 16; ++k4) {
            float4 z0 = *(const float4*)&e_lds[er +  0][4 * k4];
            float4 z1 = *(const float4*)&e_lds[er + 16][4 * k4];
            float4 z2 = *(const float4*)&e_lds[er + 32][4 * k4];
            float4 z3 = *(const float4*)&e_lds[er + 48][4 * k4];
            const float zr[4][4] = {
                {z0.x, z0.y, z0.z, z0.w},
                {z1.x, z1.y, z1.z, z1.w},
                {z2.x, z2.y, z2.z, z2.w},
                {z3.x, z3.y, z3.z, z3.w}};
#pragma unroll
            for (int jj = 0; jj < 4; ++jj) {
                float4 w0v = *(const float4*)&w0_lds[4 * k4 + jj][d0];
#pragma unroll
                for (int i = 0; i < 4; ++i) {
                    float zj = zr[i][jj];
                    acc0[i][0] = fmaf(zj, w0v.x, acc0[i][0]);
                    acc0[i][1] = fmaf(zj, w0v.y, acc0[i][1]);
                    acc0[i][2] = fmaf(zj, w0v.z, acc0[i][2]);
                    acc0[i][3] = fmaf(zj, w0v.w, acc0[i][3]);
                }
            }
        }

        float4 av0 = *(const float4*)(att0 + head * 64 + d0);
#pragma unroll
        for (int i = 0; i < 4; ++i) {
            float v = fast_tanh(acc0[i][0]) * av0.x
                    + fast_tanh(acc0[i][1]) * av0.y
                    + fast_tanh(acc0[i][2]) * av0.z
                    + fast_tanh(acc0[i][3]) * av0.w;
            v += __shfl_xor(v, 16, 64);
            v += __shfl_xor(v, 32, 64);
            p0s[head][i] = v;
        }
        __syncthreads();
    }

    if (lane < 16) {
#pragma unroll
        for (int h = 0; h < 4; ++h)
#pragma unroll
            for (int i = 0; i < 4; ++i)
                red[wv][h][lane + 16 * i] = p0s[h][i];
    }
    __syncthreads();
    if (t < 64) {
        int row = base + t;
        if (row < nrows) {
            float4 pv;
            pv.x = red[0][0][t] + red[1][0][t] + red[2][0][t] + red[3][0][t];
            pv.y = red[0][1][t] + red[1][1][t] + red[2][1][t] + red[3][1][t];
            pv.z = red[0][2][t] + red[1][2][t] + red[2][2][t] + red[3][2][t];
            pv.w = red[0][3][t] + red[1][3][t] + red[2][3][t] + red[3][3][t];
            *(float4*)(p0 + (size_t)row * 4) = pv;
        }
    }
}

// ---------------------------------------------------------------------------
// Degree histogram: 1 atomic per edge.
__global__ __launch_bounds__(256) void hist_kernel(
    const int* __restrict__ eidx, int* __restrict__ counts)
{
    int e = blockIdx.x * 256 + threadIdx.x;
    if (e >= N_EDGE) return;
    atomicAdd(&counts[eidx[e]], 1);
}

// ---------------------------------------------------------------------------
// Exclusive scan of counts[N_ENT] -> row_start[N_ENT+1]. Single block.
__global__ __launch_bounds__(1024) void scan_kernel(
    const int* __restrict__ counts, int* __restrict__ row_start)
{
    __shared__ int wsum[16];
    __shared__ int carry_s;
    const int lane = threadIdx.x & 63;
    const int wid  = threadIdx.x >> 6;
    if (threadIdx.x == 0) carry_s = 0;
    __syncthreads();
    for (int base = 0; base < N_ENT; base += 4096) {
        int i0 = base + (int)threadIdx.x * 4;
        int4 v = make_int4(0, 0, 0, 0);
        if (i0 + 3 < N_ENT) v = *(const int4*)(counts + i0);
        else {
            if (i0 + 0 < N_ENT) v.x = counts[i0 + 0];
            if (i0 + 1 < N_ENT) v.y = counts[i0 + 1];
            if (i0 + 2 < N_ENT) v.z = counts[i0 + 2];
            if (i0 + 3 < N_ENT) v.w = counts[i0 + 3];
        }
        int s1 = v.x + v.y, s2 = s1 + v.z, tsum = s2 + v.w;
        int incl = tsum;
#pragma unroll
        for (int off = 1; off < 64; off <<= 1) {
            int t = __shfl_up(incl, off, 64);
            if (lane >= off) incl += t;
        }
        if (lane == 63) wsum[wid] = incl;
        __syncthreads();                              // A
        int wave_off = 0;
#pragma unroll
        for (int w = 0; w < 16; ++w)
            wave_off += (w < wid) ? wsum[w] : 0;
        int carry = carry_s;
        int excl = carry + wave_off + (incl - tsum);
        if (i0 + 3 < N_ENT) {
            *(int4*)(row_start + i0) = make_int4(excl, excl + v.x, excl + s1, excl + s2);
        } else {
            if (i0 + 0 < N_ENT) row_start[i0 + 0] = excl;
            if (i0 + 1 < N_ENT) row_start[i0 + 1] = excl + v.x;
            if (i0 + 2 < N_ENT) row_start[i0 + 2] = excl + s1;
            if (i0 + 3 < N_ENT) row_start[i0 + 3] = excl + s2;
        }
        __syncthreads();                              // B
        if (threadIdx.x == 1023) carry_s = carry + wave_off + incl;
    }
    __syncthreads();
    if (threadIdx.x == 0) row_start[N_ENT] = carry_s;
}

// ---------------------------------------------------------------------------
// Per-edge: compute exp(leaky(score)) directly and scatter RAW exp into CSR.
__global__ __launch_bounds__(256) void scatter_score_kernel(
    const int* __restrict__ eidx, const int* __restrict__ etype,
    const float* __restrict__ ph, const float* __restrict__ pt,
    const float* __restrict__ pr,
    const int* __restrict__ row_start, int* __restrict__ cursor,
    int* __restrict__ csr_col, float* __restrict__ csr_a)
{
    int e = blockIdx.x * 256 + threadIdx.x;
    if (e >= N_EDGE) return;
    int hn = eidx[e];
    int tn = eidx[N_EDGE + e];
    int r  = etype[e];
    float4 a = *(const float4*)(ph + (size_t)hn * 4);
    float4 b = *(const float4*)(pt + (size_t)tn * 4);
    float4 c = *(const float4*)(pr + (size_t)r * 4);
    float s0 = a.x + b.x + c.x;
    float s1 = a.y + b.y + c.y;
    float s2 = a.z + b.z + c.z;
    float s3 = a.w + b.w + c.w;
    s0 = s0 >= 0.f ? s0 : 0.01f * s0;
    s1 = s1 >= 0.f ? s1 : 0.01f * s1;
    s2 = s2 >= 0.f ? s2 : 0.01f * s2;
    s3 = s3 >= 0.f ? s3 : 0.01f * s3;
    float4 ev = make_float4(__expf(s0), __expf(s1), __expf(s2), __expf(s3));
    int pos = row_start[hn] + atomicAdd(&cursor[hn], 1);
    csr_col[pos] = tn;
    *(float4*)(csr_a + (size_t)pos * 4) = ev;
}

// ---------------------------------------------------------------------------
// Row-wise softmax normalize: csr_a[p][h] *= 0.9 / (sum_row csr_a[.][h] + eps)
__global__ __launch_bounds__(256) void normalize_kernel(
    const int* __restrict__ row_start, float* __restrict__ csr_a)
{
    const int wid  = threadIdx.x >> 6;
    const int lane = threadIdx.x & 63;
    const int n = blockIdx.x * 4 + wid;
    if (n >= N_ENT) return;
    const int s   = row_start[n];
    const int end = row_start[n + 1];
    const int nf  = (end - s) * 4;          // floats in this row

    float sum = 0.f;
    for (int f = lane; f < nf; f += 64)
        sum += csr_a[(size_t)s * 4 + f];
#pragma unroll
    for (int off = 4; off < 64; off <<= 1)
        sum += __shfl_xor(sum, off, 64);
    float scale = 0.9f / (sum + 1e-16f);
    for (int f = lane; f < nf; f += 64)
        csr_a[(size_t)s * 4 + f] *= scale;
}

// ---------------------------------------------------------------------------
// SpMM step. Wave per entity; lane handles cols 4*lane..+3, h = lane/16.
template <bool IN_HALF, bool OUT_HALF>
__global__ __launch_bounds__(256) void spmm_kernel(
    const void* __restrict__ Zin_v, const float* __restrict__ emb,
    const int* __restrict__ row_start, const int* __restrict__ csr_col,
    const float* __restrict__ csr_a, void* __restrict__ Zout_v)
{
    const int wave = threadIdx.x >> 6;
    const int lane = threadIdx.x & 63;
    const int n = blockIdx.x * 4 + wave;
    const int h = lane >> 4;
    const __half* Zin_h = (const __half*)Zin_v;

    const float4* e4 = (const float4*)emb;   // [N][16]
    float4 zi = e4[(size_t)n * 16 + (lane & 15)];
    float4 acc0 = make_float4(0.1f * zi.x, 0.1f * zi.y, 0.1f * zi.z, 0.1f * zi.w);
    float4 acc1 = make_float4(0.f, 0.f, 0.f, 0.f);
    float4 acc2 = make_float4(0.f, 0.f, 0.f, 0.f);
    float4 acc3 = make_float4(0.f, 0.f, 0.f, 0.f);

    const int s   = row_start[n];
    const int end = row_start[n + 1];

    auto zrow = [&](int c) -> float4 {
        if (IN_HALF) {
            uint2 u = *(const uint2*)(Zin_h + (size_t)c * 256 + 4 * lane);
            return unpack_half4(u);
        } else {
            return *(const float4*)(emb + (size_t)c * 64 + 4 * (lane & 15));
        }
    };
    auto fma4 = [](float4& acc, float a, const float4& z) {
        acc.x = fmaf(a, z.x, acc.x);
        acc.y = fmaf(a, z.y, acc.y);
        acc.z = fmaf(a, z.z, acc.z);
        acc.w = fmaf(a, z.w, acc.w);
    };

    for (int b = s; b < end; b += 16) {
        const int nb = min(16, end - b);
        int   cl = (lane < nb) ? csr_col[b + lane] : 0;
        float al = (lane < nb * 4) ? csr_a[(size_t)b * 4 + lane] : 0.f;

        int j = 0;
        for (; j + 4 <= nb; j += 4) {
            int c0 = __shfl(cl, j + 0, 64);
            int c1 = __shfl(cl, j + 1, 64);
            int c2 = __shfl(cl, j + 2, 64);
            int c3 = __shfl(cl, j + 3, 64);
            float a0 = __shfl(al, (j + 0) * 4 + h, 64);
            float a1 = __shfl(al, (j + 1) * 4 + h, 64);
            float a2 = __shfl(al, (j + 2) * 4 + h, 64);
            float a3 = __shfl(al, (j + 3) * 4 + h, 64);
            float4 za = zrow(c0);
            float4 zb = zrow(c1);
            float4 zc = zrow(c2);
            float4 zd = zrow(c3);
            fma4(acc0, a0, za);
            fma4(acc1, a1, zb);
            fma4(acc2, a2, zc);
            fma4(acc3, a3, zd);
        }
        if (j + 0 < nb) {
            int c = __shfl(cl, j + 0, 64);
            float a = __shfl(al, (j + 0) * 4 + h, 64);
            float4 z = zrow(c);
            fma4(acc0, a, z);
        }
        if (j + 1 < nb) {
            int c = __shfl(cl, j + 1, 64);
            float a = __shfl(al, (j + 1) * 4 + h, 64);
            float4 z = zrow(c);
            fma4(acc1, a, z);
        }
        if (j + 2 < nb) {
            int c = __shfl(cl, j + 2, 64);
            float a = __shfl(al, (j + 2) * 4 + h, 64);
            float4 z = zrow(c);
            fma4(acc2, a, z);
        }
    }
    acc0.x += acc1.x + acc2.x + acc3.x;
    acc0.y += acc1.y + acc2.y + acc3.y;
    acc0.z += acc1.z + acc2.z + acc3.z;
    acc0.w += acc1.w + acc2.w + acc3.w;

    if (OUT_HALF)
        *(uint2*)((__half*)Zout_v + (size_t)n * 256 + 4 * lane) = pack_half4(acc0);
    else
        *(float4*)((float*)Zout_v + (size_t)n * 256 + 4 * lane) = acc0;
}

// ---------------------------------------------------------------------------
// out[100000,64] = Z[100000,256] @ Wo[256,64]. K in 4 chunks of 64 via LDS.
__global__ __launch_bounds__(256) void outproj_kernel(
    const float* __restrict__ Z, const float* __restrict__ Wo,
    float* __restrict__ out)
{
    __shared__ float z_lds[64][68];
    __shared__ float w_lds[64][64];
    const int t = threadIdx.x;
    const int base = blockIdx.x * 64;
    const int er = t & 15;
    const int d0 = (t >> 4) * 4;

    float acc[4][4] = {};
    for (int kc = 0; kc < 4; ++kc) {
        {
            const float4* src = (const float4*)(Wo + (size_t)kc * 64 * 64);
            float4* dst = (float4*)&w_lds[0][0];
#pragma unroll
            for (int i = 0; i < 4; ++i)
                dst[t + 256 * i] = src[t + 256 * i];
        }
        {
#pragma unroll
            for (int i = 0; i < 4; ++i) {
                int f = t + 256 * i;
                int row = f >> 4, c4 = f & 15;
                int gr = min(base + row, N_ENT - 1);
                float4 v = *(const float4*)(Z + (size_t)gr * 256 + kc * 64 + 4 * c4);
                *(float4*)&z_lds[row][4 * c4] = v;
            }
        }
        __syncthreads();

        for (int k4 = 0; k4 < 16; ++k4) {
            float4 z0 = *(const float4*)&z_lds[er +  0][4 * k4];
            float4 z1 = *(const float4*)&z_lds[er + 16][4 * k4];
            float4 z2 = *(const float4*)&z_lds[er + 32][4 * k4];
            float4 z3 = *(const float4*)&z_lds[er + 48][4 * k4];
#pragma unroll
            for (int jj = 0; jj < 4; ++jj) {
                float4 wv = *(const float4*)&w_lds[4 * k4 + jj][d0];
                float zj0 = ((const float*)&z0)[jj];
                float zj1 = ((const float*)&z1)[jj];
                float zj2 = ((const float*)&z2)[jj];
                float zj3 = ((const float*)&z3)[jj];
                acc[0][0] = fmaf(zj0, wv.x, acc[0][0]);
                acc[0][1] = fmaf(zj0, wv.y, acc[0][1]);
                acc[0][2] = fmaf(zj0, wv.z, acc[0][2]);
                acc[0][3] = fmaf(zj0, wv.w, acc[0][3]);
                acc[1][0] = fmaf(zj1, wv.x, acc[1][0]);
                acc[1][1] = fmaf(zj1, wv.y, acc[1][1]);
                acc[1][2] = fmaf(zj1, wv.z, acc[1][2]);
                acc[1][3] = fmaf(zj1, wv.w, acc[1][3]);
                acc[2][0] = fmaf(zj2, wv.x, acc[2][0]);
                acc[2][1] = fmaf(zj2, wv.y, acc[2][1]);
                acc[2][2] = fmaf(zj2, wv.z, acc[2][2]);
                acc[2][3] = fmaf(zj2, wv.w, acc[2][3]);
                acc[3][0] = fmaf(zj3, wv.x, acc[3][0]);
                acc[3][1] = fmaf(zj3, wv.y, acc[3][1]);
                acc[3][2] = fmaf(zj3, wv.z, acc[3][2]);
                acc[3][3] = fmaf(zj3, wv.w, acc[3][3]);
            }
        }
        __syncthreads();
    }

#pragma unroll
    for (int i = 0; i < 4; ++i) {
        int row = base + er + 16 * i;
        if (row < N_ENT) {
            *(float4*)(out + (size_t)row * 64 + d0) =
                make_float4(acc[i][0], acc[i][1], acc[i][2], acc[i][3]);
        }
    }
}

// ---------------------------------------------------------------------------
extern "C" void kernel_launch(void* const* d_in, const int* in_sizes, int n_in,
                              void* d_out, int out_size, void* d_ws, size_t ws_size,
                              hipStream_t stream)
{
    const float* entity = (const float*)d_in[0];
    const float* rel    = (const float*)d_in[1];
    const float* W_h    = (const float*)d_in[2];
    const float* W_t    = (const float*)d_in[3];
    const float* W_r    = (const float*)d_in[4];
    const float* att_h  = (const float*)d_in[5];
    const float* att_t  = (const float*)d_in[6];
    const float* att_r  = (const float*)d_in[7];
    const float* W_o    = (const float*)d_in[8];
    const int*   eidx   = (const int*)d_in[9];   // [2,E]
    const int*   etype  = (const int*)d_in[10];  // [E]
    float* out = (float*)d_out;

    char* ws = (char*)d_ws;
    size_t off = 0;
    auto alloc = [&](size_t bytes) -> void* {
        void* p = ws + off;
        off += (bytes + 255) & ~(size_t)255;
        return p;
    };
    float* p_h      = (float*)alloc((size_t)N_ENT * 4 * 4);
    float* p_t      = (float*)alloc((size_t)N_ENT * 4 * 4);
    float* p_r      = (float*)alloc((size_t)N_REL * 4 * 4);
    int*   counts   = (int*)alloc((size_t)N_ENT * 4);
    int*   row_start= (int*)alloc(((size_t)N_ENT + 1) * 4);
    int*   cursor   = (int*)alloc((size_t)N_ENT * 4);
    int*   csr_col  = (int*)alloc((size_t)N_EDGE * 4);
    float* csr_a    = (float*)alloc((size_t)N_EDGE * 4 * 4);
    float* Zf       = (float*)alloc((size_t)N_ENT * 256 * 4);
    __half* Zh_b    = (__half*)Zf;               // aliases Zf (dead before i5 writes Zf)
    __half* Zh_a    = (__half*)alloc((size_t)N_ENT * 256 * 2);
    unsigned short* emb_bf = (unsigned short*)alloc((size_t)N_ENT * 64 * 2);
    unsigned short* wT     = (unsigned short*)alloc((size_t)2 * 256 * 64 * 2);

    hipMemsetAsync(counts, 0, (size_t)N_ENT * 4, stream);
    hipMemsetAsync(cursor, 0, (size_t)N_ENT * 4, stream);

    // bf16 prep
    cvt_emb_kernel<<<2048, 256, 0, stream>>>(entity, emb_bf, N_ENT * 64 / 4);
    cvt_wT_kernel<<<(2 * 256 * 64 + 255) / 256, 256, 0, stream>>>(W_h, W_t, wT);

    // projections: h/t via MFMA, relations via VALU
    proj_mfma_kernel<<<(N_ENT + 63) / 64, 256, 0, stream>>>(
        emb_bf, wT, att_h, att_t, p_h, p_t, N_ENT);
    proj_gemm_kernel<<<(N_REL + 63) / 64, 256, 0, stream>>>(
        rel, W_r, att_r, p_r, N_REL);

    hist_kernel<<<(N_EDGE + 255) / 256, 256, 0, stream>>>(eidx, counts);
    scan_kernel<<<1, 1024, 0, stream>>>(counts, row_start);
    scatter_score_kernel<<<(N_EDGE + 255) / 256, 256, 0, stream>>>(
        eidx, etype, p_h, p_t, p_r, row_start, cursor, csr_col, csr_a);
    normalize_kernel<<<(N_ENT + 3) / 4, 256, 0, stream>>>(row_start, csr_a);

    // power iteration: Z1..Z5. Intermediates fp16, final fp32.
    spmm_kernel<false, true ><<<N_ENT / 4, 256, 0, stream>>>(nullptr, entity, row_start, csr_col, csr_a, Zh_b);
    spmm_kernel<true,  true ><<<N_ENT / 4, 256, 0, stream>>>(Zh_b, entity, row_start, csr_col, csr_a, Zh_a);
    spmm_kernel<true,  true ><<<N_ENT / 4, 256, 0, stream>>>(Zh_a, entity, row_start, csr_col, csr_a, Zh_b);
    spmm_kernel<true,  true ><<<N_ENT / 4, 256, 0, stream>>>(Zh_b, entity, row_start, csr_col, csr_a, Zh_a);
    spmm_kernel<true,  false><<<N_ENT / 4, 256, 0, stream>>>(Zh_a, entity, row_start, csr_col, csr_a, Zf);

    outproj_kernel<<<(N_ENT + 63) / 64, 256, 0, stream>>>(Zf, W_o, out);
}

// Round 8
// 460.780 us; speedup vs baseline: 3.0422x; 1.0803x over previous
//
#include <hip/hip_runtime.h>
#include <hip/hip_fp16.h>
#include <math.h>

#define N_ENT 100000
#define N_EDGE 500000
#define N_REL 200
// DIM=64, HEADS=4, HD=256

typedef short bf16x8 __attribute__((ext_vector_type(8)));
typedef _Float16 f16x8 __attribute__((ext_vector_type(8)));
typedef float f32x4 __attribute__((ext_vector_type(4)));

__device__ __forceinline__ float fast_tanh(float x) {
    float xc = fminf(x, 15.f);
    float e = __expf(2.f * xc);
    return (e - 1.f) / (e + 1.f);
}

__device__ __forceinline__ unsigned short f2bf(float f) {
    unsigned u = __float_as_uint(f);
    unsigned r = u + 0x7FFF + ((u >> 16) & 1);   // round-to-nearest-even
    return (unsigned short)(r >> 16);
}

__device__ __forceinline__ uint2 pack_half4(const float4 v) {
    __half2 lo = __floats2half2_rn(v.x, v.y);
    __half2 hi = __floats2half2_rn(v.z, v.w);
    uint2 r;
    r.x = *reinterpret_cast<const unsigned int*>(&lo);
    r.y = *reinterpret_cast<const unsigned int*>(&hi);
    return r;
}

__device__ __forceinline__ float4 unpack_half4(uint2 u) {
    __half2 lo = *reinterpret_cast<const __half2*>(&u.x);
    __half2 hi = *reinterpret_cast<const __half2*>(&u.y);
    float2 a = __half22float2(lo);
    float2 b = __half22float2(hi);
    return make_float4(a.x, a.y, b.x, b.y);
}

// ---------------------------------------------------------------------------
// Convert entity_embed fp32 -> bf16 (RNE), vectorized 4/thread.
__global__ __launch_bounds__(256) void cvt_emb_kernel(
    const float* __restrict__ in, unsigned short* __restrict__ out, int nquads)
{
    for (int i = blockIdx.x * 256 + threadIdx.x; i < nquads; i += gridDim.x * 256) {
        float4 v = ((const float4*)in)[i];
        ushort4 o;
        o.x = f2bf(v.x); o.y = f2bf(v.y); o.z = f2bf(v.z); o.w = f2bf(v.w);
        ((ushort4*)out)[i] = o;
    }
}

// ---------------------------------------------------------------------------
// Build wT[(mat*256+col)*64 + k] = bf16(W_mat[k*256+col]). 32768 elems.
__global__ __launch_bounds__(256) void cvt_wT_kernel(
    const float* __restrict__ W0, const float* __restrict__ W1,
    unsigned short* __restrict__ wT)
{
    int idx = blockIdx.x * 256 + threadIdx.x;     // 0..32767
    if (idx >= 2 * 256 * 64) return;
    int mat = idx >> 14;
    int rem = idx & 16383;
    int col = rem >> 6;
    int k   = rem & 63;
    const float* W = (mat == 0) ? W0 : W1;
    wT[idx] = f2bf(W[k * 256 + col]);
}

// ---------------------------------------------------------------------------
// Build woT[d*256 + k] = fp16(Wo[k*64+d]). 16384 elems.
__global__ __launch_bounds__(256) void cvt_woT_kernel(
    const float* __restrict__ Wo, __half* __restrict__ woT)
{
    int idx = blockIdx.x * 256 + threadIdx.x;     // 0..16383
    if (idx >= 64 * 256) return;
    int d = idx >> 8;
    int k = idx & 255;
    woT[idx] = __float2half(Wo[k * 64 + d]);
}

// ---------------------------------------------------------------------------
// MFMA attention projections for h and t (shared A = entity embed).
// Wave owns 16 entity rows. C layout (HW-verified): col=lane&15,
// row=(lane>>4)*4+reg. Epilogue: accumulate tanh*att across subs in regs,
// ONE 4-shfl reduce per (mat,head,j) -> 128 shuffles/wave (was 512).
__global__ __launch_bounds__(256) void proj_mfma_kernel(
    const unsigned short* __restrict__ emb_bf,   // [N][64] bf16
    const unsigned short* __restrict__ wT,       // [2*256][64] bf16
    const float* __restrict__ att0, const float* __restrict__ att1,
    float* __restrict__ p0, float* __restrict__ p1, int nrows)
{
    const int wv   = threadIdx.x >> 6;
    const int lane = threadIdx.x & 63;
    const int r4   = lane >> 4;        // k-group / C-row-quad selector
    const int cl   = lane & 15;        // A-row / B-col / C-col selector
    const int rowbase = blockIdx.x * 64 + wv * 16;

    int ra = min(rowbase + cl, nrows - 1);
    bf16x8 a0 = *(const bf16x8*)(emb_bf + (size_t)ra * 64 + 8 * r4);
    bf16x8 a1 = *(const bf16x8*)(emb_bf + (size_t)ra * 64 + 8 * r4 + 32);

#pragma unroll
    for (int mat = 0; mat < 2; ++mat) {
        const float* att = (mat == 0) ? att0 : att1;
        float* p         = (mat == 0) ? p0 : p1;
        float pacc[4][4];   // [head][j]
#pragma unroll
        for (int head = 0; head < 4; ++head) {
            float vsum[4] = {0.f, 0.f, 0.f, 0.f};
#pragma unroll
            for (int sub = 0; sub < 4; ++sub) {
                int col = head * 64 + sub * 16 + cl;
                const unsigned short* wp =
                    wT + ((size_t)(mat * 256 + col)) * 64 + 8 * r4;
                bf16x8 b0 = *(const bf16x8*)(wp);
                bf16x8 b1 = *(const bf16x8*)(wp + 32);
                f32x4 c = {0.f, 0.f, 0.f, 0.f};
                c = __builtin_amdgcn_mfma_f32_16x16x32_bf16(a0, b0, c, 0, 0, 0);
                c = __builtin_amdgcn_mfma_f32_16x16x32_bf16(a1, b1, c, 0, 0, 0);
                float av = att[head * 64 + sub * 16 + cl];
#pragma unroll
                for (int j = 0; j < 4; ++j)
                    vsum[j] = fmaf(fast_tanh(c[j]), av, vsum[j]);
            }
#pragma unroll
            for (int j = 0; j < 4; ++j) {
                float v = vsum[j];
                v += __shfl_xor(v, 1, 64);
                v += __shfl_xor(v, 2, 64);
                v += __shfl_xor(v, 4, 64);
                v += __shfl_xor(v, 8, 64);
                pacc[head][j] = v;
            }
        }
        if (cl == 0) {
#pragma unroll
            for (int j = 0; j < 4; ++j) {
                int row = rowbase + r4 * 4 + j;
                if (row < nrows) {
                    *(float4*)(p + (size_t)row * 4) = make_float4(
                        pacc[0][j], pacc[1][j], pacc[2][j], pacc[3][j]);
                }
            }
        }
    }
}

// ---------------------------------------------------------------------------
// VALU projection for relations (only 200 rows — not worth MFMA).
__global__ __launch_bounds__(256) void proj_gemm_kernel(
    const float* __restrict__ emb,     // [nrows,64]
    const float* __restrict__ W0,      // [64,256]
    const float* __restrict__ att0,    // [4,64]
    float* __restrict__ p0,            // [nrows,4]
    int nrows)
{
    __shared__ float e_lds[64][68];
    __shared__ float w0_lds[64][64];
    __shared__ float red[4][4][64];    // [wave][head][er+16*i]

    const int t    = threadIdx.x;
    const int wv   = t >> 6;
    const int lane = t & 63;
    const int er   = t & 15;
    const int d0   = (t >> 4) * 4;
    const int base = blockIdx.x * 64;

#pragma unroll
    for (int i = 0; i < 4; ++i) {
        int f = t + 256 * i;
        int row = f >> 4, c4 = f & 15;
        int gr = min(base + row, nrows - 1);
        float4 v = *(const float4*)(emb + (size_t)gr * 64 + 4 * c4);
        *(float4*)&e_lds[row][4 * c4] = v;
    }

    float p0s[4][4];

    for (int head = 0; head < 4; ++head) {
        {
            int k0 = t >> 4, c4 = t & 15;
#pragma unroll
            for (int kk = 0; kk < 4; ++kk) {
                int k = k0 + 16 * kk;
                *(float4*)&w0_lds[k][4 * c4] =
                    *(const float4*)(W0 + (size_t)k * 256 + head * 64 + 4 * c4);
            }
        }
        __syncthreads();

        float acc0[4][4] = {};
        for (int k4 = 0; k4 < 16; ++k4) {
            float4 z0 = *(const float4*)&e_lds[er +  0][4 * k4];
            float4 z1 = *(const float4*)&e_lds[er + 16][4 * k4];
            float4 z2 = *(const float4*)&e_lds[er + 32][4 * k4];
            float4 z3 = *(const float4*)&e_lds[er + 48][4 * k4];
            const float zr[4][4] = {
                {z0.x, z0.y, z0.z, z0.w},
                {z1.x, z1.y, z1.z, z1.w},
                {z2.x, z2.y, z2.z, z2.w},
                {z3.x, z3.y, z3.z, z3.w}};
#pragma unroll
            for (int jj = 0; jj < 4; ++jj) {
                float4 w0v = *(const float4*)&w0_lds[4 * k4 + jj][d0];
#pragma unroll
                for (int i = 0; i < 4; ++i) {
                    float zj = zr[i][jj];
                    acc0[i][0] = fmaf(zj, w0v.x, acc0[i][0]);
                    acc0[i][1] = fmaf(zj, w0v.y, acc0[i][1]);
                    acc0[i][2] = fmaf(zj, w0v.z, acc0[i][2]);
                    acc0[i][3] = fmaf(zj, w0v.w, acc0[i][3]);
                }
            }
        }

        float4 av0 = *(const float4*)(att0 + head * 64 + d0);
#pragma unroll
        for (int i = 0; i < 4; ++i) {
            float v = fast_tanh(acc0[i][0]) * av0.x
                    + fast_tanh(acc0[i][1]) * av0.y
                    + fast_tanh(acc0[i][2]) * av0.z
                    + fast_tanh(acc0[i][3]) * av0.w;
            v += __shfl_xor(v, 16, 64);
            v += __shfl_xor(v, 32, 64);
            p0s[head][i] = v;
        }
        __syncthreads();
    }

    if (lane < 16) {
#pragma unroll
        for (int h = 0; h < 4; ++h)
#pragma unroll
            for (int i = 0; i < 4; ++i)
                red[wv][h][lane + 16 * i] = p0s[h][i];
    }
    __syncthreads();
    if (t < 64) {
        int row = base + t;
        if (row < nrows) {
            float4 pv;
            pv.x = red[0][0][t] + red[1][0][t] + red[2][0][t] + red[3][0][t];
            pv.y = red[0][1][t] + red[1][1][t] + red[2][1][t] + red[3][1][t];
            pv.z = red[0][2][t] + red[1][2][t] + red[2][2][t] + red[3][2][t];
            pv.w = red[0][3][t] + red[1][3][t] + red[2][3][t] + red[3][3][t];
            *(float4*)(p0 + (size_t)row * 4) = pv;
        }
    }
}

// ---------------------------------------------------------------------------
// Degree histogram: 1 atomic per edge.
__global__ __launch_bounds__(256) void hist_kernel(
    const int* __restrict__ eidx, int* __restrict__ counts)
{
    int e = blockIdx.x * 256 + threadIdx.x;
    if (e >= N_EDGE) return;
    atomicAdd(&counts[eidx[e]], 1);
}

// ---------------------------------------------------------------------------
// Exclusive scan of counts[N_ENT] -> row_start[N_ENT+1]. Single block.
__global__ __launch_bounds__(1024) void scan_kernel(
    const int* __restrict__ counts, int* __restrict__ row_start)
{
    __shared__ int wsum[16];
    __shared__ int carry_s;
    const int lane = threadIdx.x & 63;
    const int wid  = threadIdx.x >> 6;
    if (threadIdx.x == 0) carry_s = 0;
    __syncthreads();
    for (int base = 0; base < N_ENT; base += 4096) {
        int i0 = base + (int)threadIdx.x * 4;
        int4 v = make_int4(0, 0, 0, 0);
        if (i0 + 3 < N_ENT) v = *(const int4*)(counts + i0);
        else {
            if (i0 + 0 < N_ENT) v.x = counts[i0 + 0];
            if (i0 + 1 < N_ENT) v.y = counts[i0 + 1];
            if (i0 + 2 < N_ENT) v.z = counts[i0 + 2];
            if (i0 + 3 < N_ENT) v.w = counts[i0 + 3];
        }
        int s1 = v.x + v.y, s2 = s1 + v.z, tsum = s2 + v.w;
        int incl = tsum;
#pragma unroll
        for (int off = 1; off < 64; off <<= 1) {
            int t = __shfl_up(incl, off, 64);
            if (lane >= off) incl += t;
        }
        if (lane == 63) wsum[wid] = incl;
        __syncthreads();                              // A
        int wave_off = 0;
#pragma unroll
        for (int w = 0; w < 16; ++w)
            wave_off += (w < wid) ? wsum[w] : 0;
        int carry = carry_s;
        int excl = carry + wave_off + (incl - tsum);
        if (i0 + 3 < N_ENT) {
            *(int4*)(row_start + i0) = make_int4(excl, excl + v.x, excl + s1, excl + s2);
        } else {
            if (i0 + 0 < N_ENT) row_start[i0 + 0] = excl;
            if (i0 + 1 < N_ENT) row_start[i0 + 1] = excl + v.x;
            if (i0 + 2 < N_ENT) row_start[i0 + 2] = excl + s1;
            if (i0 + 3 < N_ENT) row_start[i0 + 3] = excl + s2;
        }
        __syncthreads();                              // B
        if (threadIdx.x == 1023) carry_s = carry + wave_off + incl;
    }
    __syncthreads();
    if (threadIdx.x == 0) row_start[N_ENT] = carry_s;
}

// ---------------------------------------------------------------------------
// Per-edge: compute exp(leaky(score)) directly and scatter RAW exp into CSR.
__global__ __launch_bounds__(256) void scatter_score_kernel(
    const int* __restrict__ eidx, const int* __restrict__ etype,
    const float* __restrict__ ph, const float* __restrict__ pt,
    const float* __restrict__ pr,
    const int* __restrict__ row_start, int* __restrict__ cursor,
    int* __restrict__ csr_col, float* __restrict__ csr_a)
{
    int e = blockIdx.x * 256 + threadIdx.x;
    if (e >= N_EDGE) return;
    int hn = eidx[e];
    int tn = eidx[N_EDGE + e];
    int r  = etype[e];
    float4 a = *(const float4*)(ph + (size_t)hn * 4);
    float4 b = *(const float4*)(pt + (size_t)tn * 4);
    float4 c = *(const float4*)(pr + (size_t)r * 4);
    float s0 = a.x + b.x + c.x;
    float s1 = a.y + b.y + c.y;
    float s2 = a.z + b.z + c.z;
    float s3 = a.w + b.w + c.w;
    s0 = s0 >= 0.f ? s0 : 0.01f * s0;
    s1 = s1 >= 0.f ? s1 : 0.01f * s1;
    s2 = s2 >= 0.f ? s2 : 0.01f * s2;
    s3 = s3 >= 0.f ? s3 : 0.01f * s3;
    float4 ev = make_float4(__expf(s0), __expf(s1), __expf(s2), __expf(s3));
    int pos = row_start[hn] + atomicAdd(&cursor[hn], 1);
    csr_col[pos] = tn;
    *(float4*)(csr_a + (size_t)pos * 4) = ev;
}

// ---------------------------------------------------------------------------
// Row-wise softmax normalize: csr_a[p][h] *= 0.9 / (sum_row csr_a[.][h] + eps)
__global__ __launch_bounds__(256) void normalize_kernel(
    const int* __restrict__ row_start, float* __restrict__ csr_a)
{
    const int wid  = threadIdx.x >> 6;
    const int lane = threadIdx.x & 63;
    const int n = blockIdx.x * 4 + wid;
    if (n >= N_ENT) return;
    const int s   = row_start[n];
    const int end = row_start[n + 1];
    const int nf  = (end - s) * 4;          // floats in this row

    float sum = 0.f;
    for (int f = lane; f < nf; f += 64)
        sum += csr_a[(size_t)s * 4 + f];
#pragma unroll
    for (int off = 4; off < 64; off <<= 1)
        sum += __shfl_xor(sum, off, 64);
    float scale = 0.9f / (sum + 1e-16f);
    for (int f = lane; f < nf; f += 64)
        csr_a[(size_t)s * 4 + f] *= scale;
}

// ---------------------------------------------------------------------------
// SpMM step. Wave per entity; lane handles cols 4*lane..+3, h = lane/16.
template <bool IN_HALF, bool OUT_HALF>
__global__ __launch_bounds__(256) void spmm_kernel(
    const void* __restrict__ Zin_v, const float* __restrict__ emb,
    const int* __restrict__ row_start, const int* __restrict__ csr_col,
    const float* __restrict__ csr_a, void* __restrict__ Zout_v)
{
    const int wave = threadIdx.x >> 6;
    const int lane = threadIdx.x & 63;
    const int n = blockIdx.x * 4 + wave;
    const int h = lane >> 4;
    const __half* Zin_h = (const __half*)Zin_v;

    const float4* e4 = (const float4*)emb;   // [N][16]
    float4 zi = e4[(size_t)n * 16 + (lane & 15)];
    float4 acc0 = make_float4(0.1f * zi.x, 0.1f * zi.y, 0.1f * zi.z, 0.1f * zi.w);
    float4 acc1 = make_float4(0.f, 0.f, 0.f, 0.f);
    float4 acc2 = make_float4(0.f, 0.f, 0.f, 0.f);
    float4 acc3 = make_float4(0.f, 0.f, 0.f, 0.f);

    const int s   = row_start[n];
    const int end = row_start[n + 1];

    auto zrow = [&](int c) -> float4 {
        if (IN_HALF) {
            uint2 u = *(const uint2*)(Zin_h + (size_t)c * 256 + 4 * lane);
            return unpack_half4(u);
        } else {
            return *(const float4*)(emb + (size_t)c * 64 + 4 * (lane & 15));
        }
    };
    auto fma4 = [](float4& acc, float a, const float4& z) {
        acc.x = fmaf(a, z.x, acc.x);
        acc.y = fmaf(a, z.y, acc.y);
        acc.z = fmaf(a, z.z, acc.z);
        acc.w = fmaf(a, z.w, acc.w);
    };

    for (int b = s; b < end; b += 16) {
        const int nb = min(16, end - b);
        int   cl = (lane < nb) ? csr_col[b + lane] : 0;
        float al = (lane < nb * 4) ? csr_a[(size_t)b * 4 + lane] : 0.f;

        int j = 0;
        for (; j + 4 <= nb; j += 4) {
            int c0 = __shfl(cl, j + 0, 64);
            int c1 = __shfl(cl, j + 1, 64);
            int c2 = __shfl(cl, j + 2, 64);
            int c3 = __shfl(cl, j + 3, 64);
            float a0 = __shfl(al, (j + 0) * 4 + h, 64);
            float a1 = __shfl(al, (j + 1) * 4 + h, 64);
            float a2 = __shfl(al, (j + 2) * 4 + h, 64);
            float a3 = __shfl(al, (j + 3) * 4 + h, 64);
            float4 za = zrow(c0);
            float4 zb = zrow(c1);
            float4 zc = zrow(c2);
            float4 zd = zrow(c3);
            fma4(acc0, a0, za);
            fma4(acc1, a1, zb);
            fma4(acc2, a2, zc);
            fma4(acc3, a3, zd);
        }
        if (j + 0 < nb) {
            int c = __shfl(cl, j + 0, 64);
            float a = __shfl(al, (j + 0) * 4 + h, 64);
            float4 z = zrow(c);
            fma4(acc0, a, z);
        }
        if (j + 1 < nb) {
            int c = __shfl(cl, j + 1, 64);
            float a = __shfl(al, (j + 1) * 4 + h, 64);
            float4 z = zrow(c);
            fma4(acc1, a, z);
        }
        if (j + 2 < nb) {
            int c = __shfl(cl, j + 2, 64);
            float a = __shfl(al, (j + 2) * 4 + h, 64);
            float4 z = zrow(c);
            fma4(acc2, a, z);
        }
    }
    acc0.x += acc1.x + acc2.x + acc3.x;
    acc0.y += acc1.y + acc2.y + acc3.y;
    acc0.z += acc1.z + acc2.z + acc3.z;
    acc0.w += acc1.w + acc2.w + acc3.w;

    if (OUT_HALF)
        *(uint2*)((__half*)Zout_v + (size_t)n * 256 + 4 * lane) = pack_half4(acc0);
    else
        *(float4*)((float*)Zout_v + (size_t)n * 256 + 4 * lane) = acc0;
}

// ---------------------------------------------------------------------------
// out[100000,64] = Z5[100000,256](fp16) @ Wo[256,64] via MFMA f16.
// Wave = 16 rows; A (Z rows) in 32 VGPRs; B from L2-hot woT (32 KB).
// C layout (HW-verified): col=lane&15, row=(lane>>4)*4+reg.
__global__ __launch_bounds__(256) void outproj_mfma_kernel(
    const __half* __restrict__ Z,      // [N][256] fp16
    const __half* __restrict__ woT,    // [64][256] fp16 (d-major)
    float* __restrict__ out)           // [N][64]
{
    const int wv   = threadIdx.x >> 6;
    const int lane = threadIdx.x & 63;
    const int cl   = lane & 15;
    const int r4   = lane >> 4;
    const int rowbase = blockIdx.x * 64 + wv * 16;

    int ra = min(rowbase + cl, N_ENT - 1);
    const _Float16* zp = (const _Float16*)(Z + (size_t)ra * 256);
    f16x8 a[8];
#pragma unroll
    for (int ks = 0; ks < 8; ++ks)
        a[ks] = *(const f16x8*)(zp + ks * 32 + 8 * r4);

    const _Float16* wp = (const _Float16*)woT;
#pragma unroll
    for (int st = 0; st < 4; ++st) {
        f32x4 c = {0.f, 0.f, 0.f, 0.f};
        const _Float16* wcol = wp + (size_t)(st * 16 + cl) * 256 + 8 * r4;
#pragma unroll
        for (int ks = 0; ks < 8; ++ks) {
            f16x8 b = *(const f16x8*)(wcol + ks * 32);
            c = __builtin_amdgcn_mfma_f32_16x16x32_f16(a[ks], b, c, 0, 0, 0);
        }
#pragma unroll
        for (int j = 0; j < 4; ++j) {
            int row = rowbase + r4 * 4 + j;
            if (row < N_ENT)
                out[(size_t)row * 64 + st * 16 + cl] = c[j];
        }
    }
}

// ---------------------------------------------------------------------------
extern "C" void kernel_launch(void* const* d_in, const int* in_sizes, int n_in,
                              void* d_out, int out_size, void* d_ws, size_t ws_size,
                              hipStream_t stream)
{
    const float* entity = (const float*)d_in[0];
    const float* rel    = (const float*)d_in[1];
    const float* W_h    = (const float*)d_in[2];
    const float* W_t    = (const float*)d_in[3];
    const float* W_r    = (const float*)d_in[4];
    const float* att_h  = (const float*)d_in[5];
    const float* att_t  = (const float*)d_in[6];
    const float* att_r  = (const float*)d_in[7];
    const float* W_o    = (const float*)d_in[8];
    const int*   eidx   = (const int*)d_in[9];   // [2,E]
    const int*   etype  = (const int*)d_in[10];  // [E]
    float* out = (float*)d_out;

    char* ws = (char*)d_ws;
    size_t off = 0;
    auto alloc = [&](size_t bytes) -> void* {
        void* p = ws + off;
        off += (bytes + 255) & ~(size_t)255;
        return p;
    };
    float* p_h      = (float*)alloc((size_t)N_ENT * 4 * 4);
    float* p_t      = (float*)alloc((size_t)N_ENT * 4 * 4);
    float* p_r      = (float*)alloc((size_t)N_REL * 4 * 4);
    int*   counts   = (int*)alloc((size_t)N_ENT * 4);
    int*   row_start= (int*)alloc(((size_t)N_ENT + 1) * 4);
    int*   cursor   = (int*)alloc((size_t)N_ENT * 4);
    int*   csr_col  = (int*)alloc((size_t)N_EDGE * 4);
    float* csr_a    = (float*)alloc((size_t)N_EDGE * 4 * 4);
    __half* Zh_a    = (__half*)alloc((size_t)N_ENT * 256 * 2);
    __half* Zh_b    = (__half*)alloc((size_t)N_ENT * 256 * 2);
    unsigned short* emb_bf = (unsigned short*)alloc((size_t)N_ENT * 64 * 2);
    unsigned short* wT     = (unsigned short*)alloc((size_t)2 * 256 * 64 * 2);
    __half* woT     = (__half*)alloc((size_t)64 * 256 * 2);

    hipMemsetAsync(counts, 0, (size_t)N_ENT * 4, stream);
    hipMemsetAsync(cursor, 0, (size_t)N_ENT * 4, stream);

    // bf16/fp16 prep
    cvt_emb_kernel<<<2048, 256, 0, stream>>>(entity, emb_bf, N_ENT * 64 / 4);
    cvt_wT_kernel<<<(2 * 256 * 64 + 255) / 256, 256, 0, stream>>>(W_h, W_t, wT);
    cvt_woT_kernel<<<(64 * 256 + 255) / 256, 256, 0, stream>>>(W_o, woT);

    // projections: h/t via MFMA, relations via VALU
    proj_mfma_kernel<<<(N_ENT + 63) / 64, 256, 0, stream>>>(
        emb_bf, wT, att_h, att_t, p_h, p_t, N_ENT);
    proj_gemm_kernel<<<(N_REL + 63) / 64, 256, 0, stream>>>(
        rel, W_r, att_r, p_r, N_REL);

    hist_kernel<<<(N_EDGE + 255) / 256, 256, 0, stream>>>(eidx, counts);
    scan_kernel<<<1, 1024, 0, stream>>>(counts, row_start);
    scatter_score_kernel<<<(N_EDGE + 255) / 256, 256, 0, stream>>>(
        eidx, etype, p_h, p_t, p_r, row_start, cursor, csr_col, csr_a);
    normalize_kernel<<<(N_ENT + 3) / 4, 256, 0, stream>>>(row_start, csr_a);

    // power iteration: Z1..Z5, all fp16 intermediates incl. Z5
    spmm_kernel<false, true ><<<N_ENT / 4, 256, 0, stream>>>(nullptr, entity, row_start, csr_col, csr_a, Zh_b);
    spmm_kernel<true,  true ><<<N_ENT / 4, 256, 0, stream>>>(Zh_b, entity, row_start, csr_col, csr_a, Zh_a);
    spmm_kernel<true,  true ><<<N_ENT / 4, 256, 0, stream>>>(Zh_a, entity, row_start, csr_col, csr_a, Zh_b);
    spmm_kernel<true,  true ><<<N_ENT / 4, 256, 0, stream>>>(Zh_b, entity, row_start, csr_col, csr_a, Zh_a);
    spmm_kernel<true,  true ><<<N_ENT / 4, 256, 0, stream>>>(Zh_a, entity, row_start, csr_col, csr_a, Zh_b);

    // output projection via MFMA f16
    outproj_mfma_kernel<<<(N_ENT + 63) / 64, 256, 0, stream>>>(Zh_b, woT, out);
}